// Round 9
// baseline (258.769 us; speedup 1.0000x reference)
//
#include <hip/hip_runtime.h>

namespace {

constexpr int Bsz = 8, NC = 10, BC = 80, S = 512, H = 768, G4 = 3072, H2 = 1536;
constexpr int FA_CH = 32, FA_ROWS = 16, FA_STG = 20;
constexpr int FA_BLK = BC * FA_CH;      // 2560
constexpr int XF_BLK = 960, XB_BLK = 96;
constexpr int FRONT_BLK = FA_BLK + XF_BLK + XB_BLK;  // 3616
constexpr int NBACK = 96;               // cooperative back blocks
constexpr int HP = 772;                 // LDS row pad (dwords)

typedef float f32x4 __attribute__((ext_vector_type(4)));

__device__ __forceinline__ float sigm(float x){ return 1.0f/(1.0f + __expf(-x)); }
__device__ __forceinline__ float tanh_fast(float x){ return 1.0f - 2.0f/(__expf(2.0f*x) + 1.0f); }
__device__ __forceinline__ float vdot(f32x4 a, f32x4 b){ f32x4 m = a*b; return m.x+m.y+m.z+m.w; }
__device__ __forceinline__ float wred(float v){
  #pragma unroll
  for (int m = 32; m; m >>= 1) v += __shfl_xor(v, m, 64);
  return v;
}

// ---- coherent (cross-XCD via MALL) access: sc0 sc1 (R6-proven) ----
__device__ __forceinline__ void coh_load6(f32x4 (&d)[6],
    const f32x4* p0, const f32x4* p1, const f32x4* p2,
    const f32x4* p3, const f32x4* p4, const f32x4* p5){
  asm volatile(
    "global_load_dwordx4 %0, %6, off sc0 sc1\n\t"
    "global_load_dwordx4 %1, %7, off sc0 sc1\n\t"
    "global_load_dwordx4 %2, %8, off sc0 sc1\n\t"
    "global_load_dwordx4 %3, %9, off sc0 sc1\n\t"
    "global_load_dwordx4 %4, %10, off sc0 sc1\n\t"
    "global_load_dwordx4 %5, %11, off sc0 sc1\n\t"
    "s_waitcnt vmcnt(0)"
    : "=&v"(d[0]), "=&v"(d[1]), "=&v"(d[2]), "=&v"(d[3]), "=&v"(d[4]), "=&v"(d[5])
    : "v"(p0), "v"(p1), "v"(p2), "v"(p3), "v"(p4), "v"(p5)
    : "memory");
}
__device__ __forceinline__ void coh_store1(float* p, float v){
  asm volatile("global_store_dword %0, %1, off sc0 sc1" :: "v"(p), "v"(v) : "memory");
}

// ================= Kernel 1: fusedA || xgate(fwd,bwd) — R6 VERBATIM =========
__global__ __launch_bounds__(256) void k_front(
    const float* __restrict__ tok, const float* __restrict__ w_tok,
    const float* __restrict__ b_tok, float* __restrict__ win_out,
    float* __restrict__ wpart,
    const float* __restrict__ w_ih_f, const float* __restrict__ b_ih_f, const float* __restrict__ b_hh_f,
    const float* __restrict__ w_ih_b, const float* __restrict__ b_ih_b, const float* __restrict__ b_hh_b,
    float* __restrict__ xg, float* __restrict__ gbwd, unsigned* __restrict__ ctr){
  __shared__ float smemF[FA_STG * HP];
  __shared__ float scr[FA_STG];
  __shared__ float wsh[FA_ROWS];
  int blk = blockIdx.x, tid = threadIdx.x;

  if (blk == 0 && tid < 16) ctr[tid] = 0;

  if (blk < FA_BLK){
    int bc = blk >> 5, ch = blk & 31;
    int s0 = ch * FA_ROWS;
    #pragma unroll
    for (int i = 0; i < 15; i++){
      int f = i * 256 + tid;
      int row = f / 192, c4 = f % 192;
      int gs = s0 - 2 + row;
      if (gs >= 0 && gs < S)
        *(f32x4*)&smemF[row * HP + c4 * 4] =
          *(const f32x4*)&tok[((size_t)bc * S + gs) * H + c4 * 4];
    }
    __syncthreads();
    if (tid < 80){
      int r = tid >> 2, q = tid & 3;
      int gs = s0 - 2 + r;
      const f32x4* wq = (const f32x4*)w_tok + q * 48;
      float acc = 0.f;
      #pragma unroll 8
      for (int k = 0; k < 48; k++)
        acc += vdot(*(const f32x4*)&smemF[r * HP + (q * 48 + k) * 4], wq[k]);
      acc += __shfl_xor(acc, 1, 64);
      acc += __shfl_xor(acc, 2, 64);
      if (q == 0) scr[r] = (gs >= 0 && gs < S) ? sigm(acc + b_tok[0]) : 0.f;
    }
    __syncthreads();
    if (tid < FA_ROWS){
      float w = (scr[tid] + scr[tid+1] + scr[tid+2] + scr[tid+3] + scr[tid+4]) * 0.2f;
      wsh[tid] = w;
      win_out[(size_t)bc * S + s0 + tid] = w;
    }
    __syncthreads();
    if (tid < 192){
      f32x4 acc = {0.f, 0.f, 0.f, 0.f};
      #pragma unroll
      for (int i = 0; i < FA_ROWS; i++){
        float w = wsh[i];
        f32x4 a = *(const f32x4*)&smemF[(i + 2) * HP + tid * 4];
        acc += a * w;
      }
      *(f32x4*)&wpart[((size_t)ch * BC + bc) * H + tid * 4] = acc;
    }
    return;
  }

  // ---------- xgate: thread-per-(row,batch), LDS-staged tok rows ----------
  int xb = blk - FA_BLK;
  bool fwd = (xb < XF_BLK);
  int rblk, base_bc = 0;
  const float *w, *bi, *bh; float* outp;
  if (fwd){ rblk = xb / 10; base_bc = (xb % 10) * 8; w = w_ih_f; bi = b_ih_f; bh = b_hh_f; outp = xg; }
  else    { rblk = xb - XF_BLK;                      w = w_ih_b; bi = b_ih_b; bh = b_hh_b; outp = gbwd; }
  #pragma unroll
  for (int i = 0; i < 6; i++){
    int f = i * 256 + tid;
    int bl = f / 192, c4 = f % 192;
    size_t bc = fwd ? (size_t)(base_bc + bl) : ((size_t)bl * NC + NC - 1);
    *(f32x4*)&smemF[bl * HP + c4 * 4] = *(const f32x4*)&tok[bc * (size_t)S * H + c4 * 4];
  }
  __syncthreads();
  {
    int bl = tid & 7, rl = tid >> 3;
    int r = rblk * 32 + rl;
    const f32x4* wr = (const f32x4*)(w + (size_t)r * H);
    float acc = 0.f;
    #pragma unroll 8
    for (int k = 0; k < 192; k++)
      acc += vdot(*(const f32x4*)&smemF[bl * HP + k * 4], wr[k]);
    int ob = fwd ? (base_bc + bl) : bl;
    outp[(size_t)ob * G4 + r] = acc + bi[r] + bh[r];
  }
}

// ================= Kernel 2: cooperative back (R6 + 512-thr half-split) ======
struct BackArgs {
  const float *w_sum, *b_sum, *w_proj, *b_proj;
  const float *w_hh, *xg, *gbwd, *w_cls, *b_cls, *wpart;
  float *wmean, *s1, *summ_out, *hx, *cls_out;
  unsigned *ctr;
};

__global__ __launch_bounds__(512, 1) void k_back(BackArgs A){
  __shared__ float smem[13056];                  // 52.2 KB
  float* h_sh  = smem;                           // [8][772]
  float* a_sh  = smem + 6176;                    // [8][772]
  float* c_sh  = smem + 12352;                   // [64]
  float* pg_sh = smem + 12416;                   // [640] partials (step + wmean)
  int tid = threadIdx.x, lane = tid & 63, wv = tid >> 6, blkx = blockIdx.x;

  auto gbar = [&](int slot){
    asm volatile("s_waitcnt vmcnt(0)" ::: "memory");
    __syncthreads();
    if (tid == 0){
      __hip_atomic_fetch_add(&A.ctr[slot], 1u, __ATOMIC_RELAXED, __HIP_MEMORY_SCOPE_AGENT);
      while (__hip_atomic_load(&A.ctr[slot], __ATOMIC_RELAXED, __HIP_MEMORY_SCOPE_AGENT) < (unsigned)NBACK)
        __builtin_amdgcn_s_sleep(1);
    }
    __syncthreads();
  };

  auto stage6 = [&](float* dst, const float* src){     // tid<256 only
    const f32x4* s4 = (const f32x4*)src;
    f32x4 d[6];
    coh_load6(d, s4 + tid, s4 + 256 + tid, s4 + 512 + tid,
                 s4 + 768 + tid, s4 + 1024 + tid, s4 + 1280 + tid);
    #pragma unroll
    for (int i = 0; i < 6; i++){
      int f = i * 256 + tid, b = f / 192, j4 = f % 192;
      *(f32x4*)&dst[b * HP + j4 * 4] = d[i];
    }
  };

  // step t: 512 threads, half-row split. thread = (jl, g, b, hf)
  auto do_step = [&](int t){
    int jl = tid >> 6, g = (tid >> 4) & 3, b = (tid >> 1) & 7, hf = tid & 1;
    int j = blkx * 8 + jl;
    int r = g * H + j;
    const f32x4* wr = (const f32x4*)(A.w_hh + (size_t)r * H) + hf * 96;
    const f32x4* hb = (const f32x4*)&h_sh[b * HP] + hf * 96;
    float a0 = 0.f, a1 = 0.f;
    #pragma unroll 8
    for (int k = 0; k < 96; k += 2){ a0 += vdot(hb[k], wr[k]); a1 += vdot(hb[k+1], wr[k+1]); }
    float acc = a0 + a1;
    if (hf == 0) acc += A.xg[((size_t)b * NC + t) * G4 + r];
    pg_sh[jl * 65 + g * 16 + b * 2 + hf] = acc;
    __syncthreads();
    if (tid < 64){
      int jj = tid >> 3, b2 = tid & 7;
      float gi = pg_sh[jj*65 +      b2*2] + pg_sh[jj*65 +      b2*2 + 1];
      float gf = pg_sh[jj*65 + 16 + b2*2] + pg_sh[jj*65 + 16 + b2*2 + 1];
      float gg = pg_sh[jj*65 + 32 + b2*2] + pg_sh[jj*65 + 32 + b2*2 + 1];
      float go = pg_sh[jj*65 + 48 + b2*2] + pg_sh[jj*65 + 48 + b2*2 + 1];
      float c = sigm(gf) * c_sh[tid] + sigm(gi) * tanh_fast(gg);
      c_sh[tid] = c;
      coh_store1(&A.hx[(t & 1) * (Bsz*H) + b2 * H + blkx * 8 + jj],
                 sigm(go) * tanh_fast(c));
    }
  };

  // ---- P0: wmean (parallel partials) + LSTM init (h1,c1 from xg[:,0,:]) ----
  {
    int out = tid >> 3, ps = tid & 7;            // 64 outputs x 8 p-slices
    int idx = blkx * 64 + out;
    int b = idx / H, hh = idx % H;
    float acc = 0.f;
    for (int p = ps * 4; p < ps * 4 + 4; p++)
      #pragma unroll
      for (int c = 0; c < NC; c++)
        acc += A.wpart[((size_t)p * BC + b * NC + c) * H + hh];
    pg_sh[out * 9 + ps] = acc;
  }
  __syncthreads();
  if (tid < 64){
    float acc = 0.f;
    #pragma unroll
    for (int ps = 0; ps < 8; ps++) acc += pg_sh[tid * 9 + ps];
    coh_store1(&A.wmean[blkx * 64 + tid], acc * 0.1f);
    int jl = tid >> 3, b2 = tid & 7, j = blkx * 8 + jl;
    const float* gp = A.xg + (size_t)(b2 * NC) * G4;
    float c = sigm(gp[j]) * tanh_fast(gp[2*H + j]);
    c_sh[tid] = c;
    coh_store1(&A.hx[b2 * H + j], sigm(gp[3*H + j]) * tanh_fast(c));
  }
  gbar(0);

  // ---- P1: s1 = wmean @ w_sum.T  ||  step1 ----
  if (tid < 256){ stage6(a_sh, A.wmean); stage6(h_sh, A.hx); }
  __syncthreads();
  if (tid < 256){
    int out = tid >> 2, q = tid & 3;
    int ol = out >> 3, b = out & 7;
    int o = blkx * 8 + ol;
    const f32x4* wq = (const f32x4*)(A.w_sum + (size_t)o * H) + q * 48;
    float acc = 0.f;
    #pragma unroll 8
    for (int k = 0; k < 48; k++)
      acc += vdot(*(const f32x4*)&a_sh[b * HP + (q * 48 + k) * 4], wq[k]);
    acc += __shfl_xor(acc, 1, 64);
    acc += __shfl_xor(acc, 2, 64);
    if (q == 0) coh_store1(&A.s1[(size_t)b * H + o], acc + A.b_sum[o]);
  }
  do_step(1);
  gbar(1);

  // ---- P2: summ = s1 @ w_proj.T  ||  step2 ----
  if (tid < 256){ stage6(a_sh, A.s1); stage6(h_sh, A.hx + Bsz*H); }
  __syncthreads();
  if (tid < 256){
    int out = tid >> 1, hf = tid & 1;
    int ol = out >> 3, b = out & 7;
    int o = blkx * 16 + ol;
    const f32x4* wq = (const f32x4*)(A.w_proj + (size_t)o * H) + hf * 96;
    float acc = 0.f;
    #pragma unroll 8
    for (int k = 0; k < 96; k++)
      acc += vdot(*(const f32x4*)&a_sh[b * HP + (hf * 96 + k) * 4], wq[k]);
    acc += __shfl_xor(acc, 1, 64);
    if (hf == 0) coh_store1(&A.summ_out[(size_t)b * H2 + o], acc + A.b_proj[o]);
  }
  do_step(2);
  gbar(2);

  // ---- steps 3..9 ----
  for (int t = 3; t <= 9; t++){
    if (tid < 256) stage6(h_sh, A.hx + ((t - 1) & 1) * (Bsz*H));
    __syncthreads();
    do_step(t);
    gbar(t);
  }

  // ---- fincls on block 0: comb = [h10|hb] + summ ; cls ----
  if (blkx == 0){
    float* comb = smem;                          // 12288 floats
    if (tid < 256){
      f32x4 d[6];
      const f32x4* h4 = (const f32x4*)(A.hx + Bsz*H);   // h10 (buf 1)
      coh_load6(d, h4 + tid, h4 + 256 + tid, h4 + 512 + tid,
                   h4 + 768 + tid, h4 + 1024 + tid, h4 + 1280 + tid);
      #pragma unroll
      for (int i = 0; i < 6; i++){
        int f = i * 256 + tid, b = f / 192, e = (f % 192) * 4;
        *(f32x4*)&comb[b * H2 + e] = d[i];
      }
      #pragma unroll
      for (int u = 0; u < 6; u++){               // hb from gbwd (plain loads)
        int f = u * 256 + tid;
        int b = f / 192, e = (f % 192) * 4;
        f32x4 gi = *(const f32x4*)&A.gbwd[(size_t)b * G4 + e];
        f32x4 gg = *(const f32x4*)&A.gbwd[(size_t)b * G4 + 2*H + e];
        f32x4 go = *(const f32x4*)&A.gbwd[(size_t)b * G4 + 3*H + e];
        f32x4 hb;
        hb.x = sigm(go.x) * tanh_fast(sigm(gi.x) * tanh_fast(gg.x));
        hb.y = sigm(go.y) * tanh_fast(sigm(gi.y) * tanh_fast(gg.y));
        hb.z = sigm(go.z) * tanh_fast(sigm(gi.z) * tanh_fast(gg.z));
        hb.w = sigm(go.w) * tanh_fast(sigm(gi.w) * tanh_fast(gg.w));
        *(f32x4*)&comb[b * H2 + H + e] = hb;
      }
    }
    __syncthreads();
    if (tid < 256){
      f32x4 d[6];
      const f32x4* s4 = (const f32x4*)A.summ_out;
      coh_load6(d, s4 + tid, s4 + 256 + tid, s4 + 512 + tid,
                   s4 + 768 + tid, s4 + 1024 + tid, s4 + 1280 + tid);
      #pragma unroll
      for (int i = 0; i < 6; i++) *(f32x4*)&comb[(i * 256 + tid) * 4] += d[i];
      coh_load6(d, s4 + 1536 + tid, s4 + 1792 + tid, s4 + 2048 + tid,
                   s4 + 2304 + tid, s4 + 2560 + tid, s4 + 2816 + tid);
      #pragma unroll
      for (int i = 0; i < 6; i++) *(f32x4*)&comb[(1536 + i * 256 + tid) * 4] += d[i];
    }
    __syncthreads();
    for (int b = wv; b < Bsz; b += 8){           // 8 waves, 1 batch each
      const f32x4* c4 = (const f32x4*)&comb[b * H2];
      const f32x4* wc = (const f32x4*)A.w_cls;
      float acc = 0.f;
      #pragma unroll
      for (int k = 0; k < 6; k++)
        acc += vdot(c4[lane + 64*k], wc[lane + 64*k]);
      acc = wred(acc);
      if (lane == 0) A.cls_out[b] = sigm(acc + A.b_cls[0]);
    }
  }
}

} // namespace

extern "C" void kernel_launch(void* const* d_in, const int* in_sizes, int n_in,
                              void* d_out, int out_size, void* d_ws, size_t ws_size,
                              hipStream_t stream) {
  const float* tok    = (const float*)d_in[0];
  const float* w_tok  = (const float*)d_in[1];
  const float* b_tok  = (const float*)d_in[2];
  const float* w_sum  = (const float*)d_in[3];
  const float* b_sum  = (const float*)d_in[4];
  const float* w_proj = (const float*)d_in[5];
  const float* b_proj = (const float*)d_in[6];
  const float* w_ih_f = (const float*)d_in[7];
  const float* w_hh_f = (const float*)d_in[8];
  const float* b_ih_f = (const float*)d_in[9];
  const float* b_hh_f = (const float*)d_in[10];
  const float* w_ih_b = (const float*)d_in[11];
  const float* b_ih_b = (const float*)d_in[13];
  const float* b_hh_b = (const float*)d_in[14];
  const float* w_cls  = (const float*)d_in[15];
  const float* b_cls  = (const float*)d_in[16];

  float* out      = (float*)d_out;
  float* cls_out  = out;
  float* win_out  = out + 8;
  float* summ_out = out + 8 + BC * S;

  float* ws     = (float*)d_ws;
  float* wpart  = ws;                              // 32*80*768
  float* wmean  = wpart + (size_t)FA_CH * BC * H;  // 6144
  float* s1     = wmean + Bsz * H;                 // 6144
  float* xg     = s1 + Bsz * H;                    // 245760
  float* gbwd   = xg + (size_t)BC * G4;            // 24576
  float* hx     = gbwd + (size_t)Bsz * G4;         // 12288 (2 bufs)
  unsigned* ctr = (unsigned*)(hx + 2 * Bsz * H);   // 16

  k_front<<<FRONT_BLK, 256, 0, stream>>>(tok, w_tok, b_tok, win_out, wpart,
                                         w_ih_f, b_ih_f, b_hh_f,
                                         w_ih_b, b_ih_b, b_hh_b, xg, gbwd, ctr);

  BackArgs ba;
  ba.w_sum = w_sum; ba.b_sum = b_sum; ba.w_proj = w_proj; ba.b_proj = b_proj;
  ba.w_hh = w_hh_f; ba.xg = xg; ba.gbwd = gbwd; ba.w_cls = w_cls; ba.b_cls = b_cls;
  ba.wpart = wpart; ba.wmean = wmean; ba.s1 = s1; ba.summ_out = summ_out;
  ba.hx = hx; ba.cls_out = cls_out; ba.ctr = ctr;

  void* params[] = { &ba };
  hipLaunchCooperativeKernel(reinterpret_cast<void*>(k_back),
                             dim3(NBACK), dim3(512), params, 0, stream);
}

// Round 10
// 202.998 us; speedup vs baseline: 1.2747x; 1.2747x over previous
//
#include <hip/hip_runtime.h>

namespace {

constexpr int Bsz = 8, NC = 10, BC = 80, S = 512, H = 768, G4 = 3072, H2 = 1536;
constexpr int FA_CH = 64, FA_ROWS = 8, FA_STG = 12;   // 8-row tiles + 4 halo
constexpr int FA_BLK = BC * FA_CH;      // 5120
constexpr int XF_BLK = 960, XB_BLK = 96;
constexpr int XG_BLK = XF_BLK + XB_BLK; // 1056
constexpr int NBACK = 96;               // cooperative back blocks
constexpr int HP = 772;                 // LDS row pad (dwords)

typedef float f32x4 __attribute__((ext_vector_type(4)));

__device__ __forceinline__ float sigm(float x){ return 1.0f/(1.0f + __expf(-x)); }
__device__ __forceinline__ float tanh_fast(float x){ return 1.0f - 2.0f/(__expf(2.0f*x) + 1.0f); }
__device__ __forceinline__ float vdot(f32x4 a, f32x4 b){ f32x4 m = a*b; return m.x+m.y+m.z+m.w; }
__device__ __forceinline__ float wred(float v){
  #pragma unroll
  for (int m = 32; m; m >>= 1) v += __shfl_xor(v, m, 64);
  return v;
}

// ---- coherent (cross-XCD via MALL) access: sc0 sc1 (R6-proven) ----
__device__ __forceinline__ void coh_load6(f32x4 (&d)[6],
    const f32x4* p0, const f32x4* p1, const f32x4* p2,
    const f32x4* p3, const f32x4* p4, const f32x4* p5){
  asm volatile(
    "global_load_dwordx4 %0, %6, off sc0 sc1\n\t"
    "global_load_dwordx4 %1, %7, off sc0 sc1\n\t"
    "global_load_dwordx4 %2, %8, off sc0 sc1\n\t"
    "global_load_dwordx4 %3, %9, off sc0 sc1\n\t"
    "global_load_dwordx4 %4, %10, off sc0 sc1\n\t"
    "global_load_dwordx4 %5, %11, off sc0 sc1\n\t"
    "s_waitcnt vmcnt(0)"
    : "=&v"(d[0]), "=&v"(d[1]), "=&v"(d[2]), "=&v"(d[3]), "=&v"(d[4]), "=&v"(d[5])
    : "v"(p0), "v"(p1), "v"(p2), "v"(p3), "v"(p4), "v"(p5)
    : "memory");
}
__device__ __forceinline__ void coh_store1(float* p, float v){
  asm volatile("global_store_dword %0, %1, off sc0 sc1" :: "v"(p), "v"(v) : "memory");
}

// ================= Kernel 1: fusedA, 8-row tiles (4 blocks/CU) ===============
__global__ __launch_bounds__(256) void k_fa(
    const float* __restrict__ tok, const float* __restrict__ w_tok,
    const float* __restrict__ b_tok, float* __restrict__ win_out,
    float* __restrict__ wpart, unsigned* __restrict__ ctr){
  __shared__ float smemF[FA_STG * HP];   // 37056 B
  __shared__ float scr[FA_STG];
  __shared__ float wsh[FA_ROWS];
  int blk = blockIdx.x, tid = threadIdx.x;

  if (blk == 0 && tid < 16) ctr[tid] = 0;

  int bc = blk >> 6, ch = blk & 63;
  int s0 = ch * FA_ROWS;
  #pragma unroll
  for (int i = 0; i < 9; i++){                  // stage 12 rows (halo +-2): 2304 f32x4
    int f = i * 256 + tid;
    int row = f / 192, c4 = f % 192;
    int gs = s0 - 2 + row;
    if (gs >= 0 && gs < S)
      *(f32x4*)&smemF[row * HP + c4 * 4] =
        *(const f32x4*)&tok[((size_t)bc * S + gs) * H + c4 * 4];
  }
  __syncthreads();
  if (tid < 192){                               // scores: 12 rows x 16 lanes
    int r = tid >> 4, e = tid & 15;
    int gs = s0 - 2 + r;
    const f32x4* wq = (const f32x4*)w_tok;
    float acc = 0.f;
    #pragma unroll
    for (int i = 0; i < 12; i++){
      int k = e + 16 * i;
      acc += vdot(*(const f32x4*)&smemF[r * HP + k * 4], wq[k]);
    }
    acc += __shfl_xor(acc, 1, 64);
    acc += __shfl_xor(acc, 2, 64);
    acc += __shfl_xor(acc, 4, 64);
    acc += __shfl_xor(acc, 8, 64);
    if (e == 0) scr[r] = (gs >= 0 && gs < S) ? sigm(acc + b_tok[0]) : 0.f;
  }
  __syncthreads();
  if (tid < FA_ROWS){
    float w = (scr[tid] + scr[tid+1] + scr[tid+2] + scr[tid+3] + scr[tid+4]) * 0.2f;
    wsh[tid] = w;
    win_out[(size_t)bc * S + s0 + tid] = w;
  }
  __syncthreads();
  if (tid < 192){                               // weighted partial over 8 rows
    f32x4 acc = {0.f, 0.f, 0.f, 0.f};
    #pragma unroll
    for (int i = 0; i < FA_ROWS; i++){
      float w = wsh[i];
      f32x4 a = *(const f32x4*)&smemF[(i + 2) * HP + tid * 4];
      acc += a * w;
    }
    *(f32x4*)&wpart[((size_t)ch * BC + bc) * H + tid * 4] = acc;
  }
}

// ================= Kernel 2: xgate fwd+bwd (6 blocks/CU) =====================
__global__ __launch_bounds__(256) void k_xg(
    const float* __restrict__ tok,
    const float* __restrict__ w_ih_f, const float* __restrict__ b_ih_f, const float* __restrict__ b_hh_f,
    const float* __restrict__ w_ih_b, const float* __restrict__ b_ih_b, const float* __restrict__ b_hh_b,
    float* __restrict__ xg, float* __restrict__ gbwd){
  __shared__ float smemX[8 * HP];                // 24704 B
  int blk = blockIdx.x, tid = threadIdx.x;
  bool fwd = (blk < XF_BLK);
  int rblk, base_bc = 0;
  const float *w, *bi, *bh; float* outp;
  if (fwd){ rblk = blk / 10; base_bc = (blk % 10) * 8; w = w_ih_f; bi = b_ih_f; bh = b_hh_f; outp = xg; }
  else    { rblk = blk - XF_BLK;                      w = w_ih_b; bi = b_ih_b; bh = b_hh_b; outp = gbwd; }
  #pragma unroll
  for (int i = 0; i < 6; i++){                   // stage 8 tok rows
    int f = i * 256 + tid;
    int bl = f / 192, c4 = f % 192;
    size_t bc = fwd ? (size_t)(base_bc + bl) : ((size_t)bl * NC + NC - 1);
    *(f32x4*)&smemX[bl * HP + c4 * 4] = *(const f32x4*)&tok[bc * (size_t)S * H + c4 * 4];
  }
  __syncthreads();
  {
    int bl = tid & 7, rl = tid >> 3;
    int r = rblk * 32 + rl;
    const f32x4* wr = (const f32x4*)(w + (size_t)r * H);
    float acc = 0.f;
    #pragma unroll 8
    for (int k = 0; k < 192; k++)
      acc += vdot(*(const f32x4*)&smemX[bl * HP + k * 4], wr[k]);
    int ob = fwd ? (base_bc + bl) : bl;
    outp[(size_t)ob * G4 + r] = acc + bi[r] + bh[r];
  }
}

// ================= Kernel 3: cooperative back — R6-proven structure ==========
struct BackArgs {
  const float *w_sum, *b_sum, *w_proj, *b_proj;
  const float *w_hh, *xg, *gbwd, *w_cls, *b_cls, *wpart;
  float *wmean, *s1, *summ_out, *hx, *cls_out;
  unsigned *ctr;
};

__global__ __launch_bounds__(256) void k_back(BackArgs A){
  __shared__ float smem[12992];                  // 52 KB
  float* h_sh  = smem;                           // [8][772]
  float* a_sh  = smem + 6176;                    // [8][772]
  float* c_sh  = smem + 12352;                   // [64]
  float* g_sh  = smem + 12416;                   // [8jl][4g][8b] = 256
  float* pg_sh = smem + 12672;                   // [64][5] = 320 (wmean partials)
  int tid = threadIdx.x, lane = tid & 63, wv = tid >> 6, blkx = blockIdx.x;

  auto gbar = [&](int slot){
    asm volatile("s_waitcnt vmcnt(0)" ::: "memory");
    __syncthreads();
    if (tid == 0){
      __hip_atomic_fetch_add(&A.ctr[slot], 1u, __ATOMIC_RELAXED, __HIP_MEMORY_SCOPE_AGENT);
      while (__hip_atomic_load(&A.ctr[slot], __ATOMIC_RELAXED, __HIP_MEMORY_SCOPE_AGENT) < (unsigned)NBACK)
        __builtin_amdgcn_s_sleep(1);
    }
    __syncthreads();
  };

  auto stage6 = [&](float* dst, const float* src){
    const f32x4* s4 = (const f32x4*)src;
    f32x4 d[6];
    coh_load6(d, s4 + tid, s4 + 256 + tid, s4 + 512 + tid,
                 s4 + 768 + tid, s4 + 1024 + tid, s4 + 1280 + tid);
    #pragma unroll
    for (int i = 0; i < 6; i++){
      int f = i * 256 + tid, b = f / 192, j4 = f % 192;
      *(f32x4*)&dst[b * HP + j4 * 4] = d[i];
    }
  };

  // step t: thread = (jl, g, b), full-row dot; w_hh from global (L2)
  auto do_step = [&](int t){
    int jl = tid >> 5, g = (tid >> 3) & 3, b = tid & 7;
    int j = blkx * 8 + jl;
    int r = g * H + j;
    const f32x4* wr = (const f32x4*)(A.w_hh + (size_t)r * H);
    float acc = 0.f;
    #pragma unroll 8
    for (int k = 0; k < 192; k++)
      acc += vdot(*(const f32x4*)&h_sh[b * HP + k * 4], wr[k]);
    g_sh[jl * 32 + g * 8 + b] = acc + A.xg[((size_t)b * NC + t) * G4 + r];
    __syncthreads();
    if (tid < 64){
      int jj = tid >> 3, b2 = tid & 7;
      float gi = g_sh[jj*32 + b2],      gf = g_sh[jj*32 + 8 + b2];
      float gg = g_sh[jj*32 + 16 + b2], go = g_sh[jj*32 + 24 + b2];
      float c = sigm(gf) * c_sh[tid] + sigm(gi) * tanh_fast(gg);
      c_sh[tid] = c;
      coh_store1(&A.hx[(t & 1) * (Bsz*H) + b2 * H + blkx * 8 + jj],
                 sigm(go) * tanh_fast(c));
    }
  };

  // ---- P0: wmean (parallel partials over 64 chunks) + LSTM init ----
  {
    int out = tid >> 2, ps = tid & 3;            // 64 outputs x 4 p-slices
    int idx = blkx * 64 + out;
    int b = idx / H, hh = idx % H;
    float acc = 0.f;
    for (int p = ps * 16; p < ps * 16 + 16; p++)
      #pragma unroll
      for (int c = 0; c < NC; c++)
        acc += A.wpart[((size_t)p * BC + b * NC + c) * H + hh];
    pg_sh[out * 5 + ps] = acc;
  }
  __syncthreads();
  if (tid < 64){
    float acc = pg_sh[tid*5] + pg_sh[tid*5+1] + pg_sh[tid*5+2] + pg_sh[tid*5+3];
    coh_store1(&A.wmean[blkx * 64 + tid], acc * 0.1f);
    int jl = tid >> 3, b2 = tid & 7, j = blkx * 8 + jl;
    const float* gp = A.xg + (size_t)(b2 * NC) * G4;
    float c = sigm(gp[j]) * tanh_fast(gp[2*H + j]);
    c_sh[tid] = c;
    coh_store1(&A.hx[b2 * H + j], sigm(gp[3*H + j]) * tanh_fast(c));
  }
  gbar(0);

  // ---- P1: s1 = wmean @ w_sum.T  ||  step1 ----
  stage6(a_sh, A.wmean);
  stage6(h_sh, A.hx);            // h1 (buf 0)
  __syncthreads();
  {
    int out = tid >> 2, q = tid & 3;
    int ol = out >> 3, b = out & 7;
    int o = blkx * 8 + ol;
    const f32x4* wq = (const f32x4*)(A.w_sum + (size_t)o * H) + q * 48;
    float acc = 0.f;
    #pragma unroll 8
    for (int k = 0; k < 48; k++)
      acc += vdot(*(const f32x4*)&a_sh[b * HP + (q * 48 + k) * 4], wq[k]);
    acc += __shfl_xor(acc, 1, 64);
    acc += __shfl_xor(acc, 2, 64);
    if (q == 0) coh_store1(&A.s1[(size_t)b * H + o], acc + A.b_sum[o]);
  }
  do_step(1);
  gbar(1);

  // ---- P2: summ = s1 @ w_proj.T  ||  step2 ----
  stage6(a_sh, A.s1);
  stage6(h_sh, A.hx + Bsz*H);    // h2 (buf 1)
  __syncthreads();
  {
    int out = tid >> 1, hf = tid & 1;
    int ol = out >> 3, b = out & 7;
    int o = blkx * 16 + ol;
    const f32x4* wq = (const f32x4*)(A.w_proj + (size_t)o * H) + hf * 96;
    float acc = 0.f;
    #pragma unroll 8
    for (int k = 0; k < 96; k++)
      acc += vdot(*(const f32x4*)&a_sh[b * HP + (hf * 96 + k) * 4], wq[k]);
    acc += __shfl_xor(acc, 1, 64);
    if (hf == 0) coh_store1(&A.summ_out[(size_t)b * H2 + o], acc + A.b_proj[o]);
  }
  do_step(2);
  gbar(2);

  // ---- steps 3..9 ----
  for (int t = 3; t <= 9; t++){
    stage6(h_sh, A.hx + ((t - 1) & 1) * (Bsz*H));
    __syncthreads();
    do_step(t);
    gbar(t);
  }

  // ---- fincls on block 0: comb = [h10|hb] + summ ; cls ----
  if (blkx == 0){
    float* comb = smem;                          // 12288 floats (< c_sh offset)
    {
      f32x4 d[6];
      const f32x4* h4 = (const f32x4*)(A.hx + Bsz*H);   // h10 (buf 1)
      coh_load6(d, h4 + tid, h4 + 256 + tid, h4 + 512 + tid,
                   h4 + 768 + tid, h4 + 1024 + tid, h4 + 1280 + tid);
      #pragma unroll
      for (int i = 0; i < 6; i++){
        int f = i * 256 + tid, b = f / 192, e = (f % 192) * 4;
        *(f32x4*)&comb[b * H2 + e] = d[i];
      }
      #pragma unroll
      for (int u = 0; u < 6; u++){               // hb from gbwd (plain loads)
        int f = u * 256 + tid;
        int b = f / 192, e = (f % 192) * 4;
        f32x4 gi = *(const f32x4*)&A.gbwd[(size_t)b * G4 + e];
        f32x4 gg = *(const f32x4*)&A.gbwd[(size_t)b * G4 + 2*H + e];
        f32x4 go = *(const f32x4*)&A.gbwd[(size_t)b * G4 + 3*H + e];
        f32x4 hb;
        hb.x = sigm(go.x) * tanh_fast(sigm(gi.x) * tanh_fast(gg.x));
        hb.y = sigm(go.y) * tanh_fast(sigm(gi.y) * tanh_fast(gg.y));
        hb.z = sigm(go.z) * tanh_fast(sigm(gi.z) * tanh_fast(gg.z));
        hb.w = sigm(go.w) * tanh_fast(sigm(gi.w) * tanh_fast(gg.w));
        *(f32x4*)&comb[b * H2 + H + e] = hb;
      }
    }
    __syncthreads();
    {
      f32x4 d[6];
      const f32x4* s4 = (const f32x4*)A.summ_out;
      coh_load6(d, s4 + tid, s4 + 256 + tid, s4 + 512 + tid,
                   s4 + 768 + tid, s4 + 1024 + tid, s4 + 1280 + tid);
      #pragma unroll
      for (int i = 0; i < 6; i++) *(f32x4*)&comb[(i * 256 + tid) * 4] += d[i];
      coh_load6(d, s4 + 1536 + tid, s4 + 1792 + tid, s4 + 2048 + tid,
                   s4 + 2304 + tid, s4 + 2560 + tid, s4 + 2816 + tid);
      #pragma unroll
      for (int i = 0; i < 6; i++) *(f32x4*)&comb[(1536 + i * 256 + tid) * 4] += d[i];
    }
    __syncthreads();
    for (int b = wv; b < Bsz; b += 4){
      const f32x4* c4 = (const f32x4*)&comb[b * H2];
      const f32x4* wc = (const f32x4*)A.w_cls;
      float acc = 0.f;
      #pragma unroll
      for (int k = 0; k < 6; k++)
        acc += vdot(c4[lane + 64*k], wc[lane + 64*k]);
      acc = wred(acc);
      if (lane == 0) A.cls_out[b] = sigm(acc + A.b_cls[0]);
    }
  }
}

} // namespace

extern "C" void kernel_launch(void* const* d_in, const int* in_sizes, int n_in,
                              void* d_out, int out_size, void* d_ws, size_t ws_size,
                              hipStream_t stream) {
  const float* tok    = (const float*)d_in[0];
  const float* w_tok  = (const float*)d_in[1];
  const float* b_tok  = (const float*)d_in[2];
  const float* w_sum  = (const float*)d_in[3];
  const float* b_sum  = (const float*)d_in[4];
  const float* w_proj = (const float*)d_in[5];
  const float* b_proj = (const float*)d_in[6];
  const float* w_ih_f = (const float*)d_in[7];
  const float* w_hh_f = (const float*)d_in[8];
  const float* b_ih_f = (const float*)d_in[9];
  const float* b_hh_f = (const float*)d_in[10];
  const float* w_ih_b = (const float*)d_in[11];
  const float* b_ih_b = (const float*)d_in[13];
  const float* b_hh_b = (const float*)d_in[14];
  const float* w_cls  = (const float*)d_in[15];
  const float* b_cls  = (const float*)d_in[16];

  float* out      = (float*)d_out;
  float* cls_out  = out;
  float* win_out  = out + 8;
  float* summ_out = out + 8 + BC * S;

  float* ws     = (float*)d_ws;
  float* wpart  = ws;                              // 64*80*768 = 3,932,160
  float* wmean  = wpart + (size_t)FA_CH * BC * H;  // 6144
  float* s1     = wmean + Bsz * H;                 // 6144
  float* xg     = s1 + Bsz * H;                    // 245760
  float* gbwd   = xg + (size_t)BC * G4;            // 24576
  float* hx     = gbwd + (size_t)Bsz * G4;         // 12288 (2 bufs)
  unsigned* ctr = (unsigned*)(hx + 2 * Bsz * H);   // 16

  k_fa<<<FA_BLK, 256, 0, stream>>>(tok, w_tok, b_tok, win_out, wpart, ctr);
  k_xg<<<XG_BLK, 256, 0, stream>>>(tok, w_ih_f, b_ih_f, b_hh_f,
                                   w_ih_b, b_ih_b, b_hh_b, xg, gbwd);

  BackArgs ba;
  ba.w_sum = w_sum; ba.b_sum = b_sum; ba.w_proj = w_proj; ba.b_proj = b_proj;
  ba.w_hh = w_hh_f; ba.xg = xg; ba.gbwd = gbwd; ba.w_cls = w_cls; ba.b_cls = b_cls;
  ba.wpart = wpart; ba.wmean = wmean; ba.s1 = s1; ba.summ_out = summ_out;
  ba.hx = hx; ba.cls_out = cls_out; ba.ctr = ctr;

  void* params[] = { &ba };
  hipLaunchCooperativeKernel(reinterpret_cast<void*>(k_back),
                             dim3(NBACK), dim3(256), params, 0, stream);
}

// Round 11
// 185.148 us; speedup vs baseline: 1.3976x; 1.0964x over previous
//
#include <hip/hip_runtime.h>

namespace {

constexpr int Bsz = 8, NC = 10, BC = 80, S = 512, H = 768, G4 = 3072, H2 = 1536;
constexpr int FA_CH = 64, FA_ROWS = 8, FA_STG = 12;   // 8-row tiles + 4 halo
constexpr int FA_BLK = BC * FA_CH;      // 5120
constexpr int XF_BLK = 960, XB_BLK = 96;
constexpr int XG_BLK = XF_BLK + XB_BLK; // 1056
constexpr int NBACK = 96;               // cooperative back blocks
constexpr int HP = 772;                 // LDS row pad (dwords)

typedef float f32x4 __attribute__((ext_vector_type(4)));

__device__ __forceinline__ float sigm(float x){ return 1.0f/(1.0f + __expf(-x)); }
__device__ __forceinline__ float tanh_fast(float x){ return 1.0f - 2.0f/(__expf(2.0f*x) + 1.0f); }
__device__ __forceinline__ float vdot(f32x4 a, f32x4 b){ f32x4 m = a*b; return m.x+m.y+m.z+m.w; }
__device__ __forceinline__ float hsum(f32x4 a){ return (a.x+a.y)+(a.z+a.w); }
__device__ __forceinline__ float wred(float v){
  #pragma unroll
  for (int m = 32; m; m >>= 1) v += __shfl_xor(v, m, 64);
  return v;
}

// ---- coherent (cross-XCD via MALL) access: sc0 sc1 (R6-proven) ----
__device__ __forceinline__ void coh_load6(f32x4 (&d)[6],
    const f32x4* p0, const f32x4* p1, const f32x4* p2,
    const f32x4* p3, const f32x4* p4, const f32x4* p5){
  asm volatile(
    "global_load_dwordx4 %0, %6, off sc0 sc1\n\t"
    "global_load_dwordx4 %1, %7, off sc0 sc1\n\t"
    "global_load_dwordx4 %2, %8, off sc0 sc1\n\t"
    "global_load_dwordx4 %3, %9, off sc0 sc1\n\t"
    "global_load_dwordx4 %4, %10, off sc0 sc1\n\t"
    "global_load_dwordx4 %5, %11, off sc0 sc1\n\t"
    "s_waitcnt vmcnt(0)"
    : "=&v"(d[0]), "=&v"(d[1]), "=&v"(d[2]), "=&v"(d[3]), "=&v"(d[4]), "=&v"(d[5])
    : "v"(p0), "v"(p1), "v"(p2), "v"(p3), "v"(p4), "v"(p5)
    : "memory");
}
__device__ __forceinline__ void coh_store1(float* p, float v){
  asm volatile("global_store_dword %0, %1, off sc0 sc1" :: "v"(p), "v"(v) : "memory");
}

// ================= Kernel 1: fusedA, 8-row tiles =============================
__global__ __launch_bounds__(256) void k_fa(
    const float* __restrict__ tok, const float* __restrict__ w_tok,
    const float* __restrict__ b_tok, float* __restrict__ win_out,
    float* __restrict__ wpart, unsigned* __restrict__ ctr){
  __shared__ float smemF[FA_STG * HP];   // 37056 B
  __shared__ float scr[FA_STG];
  __shared__ float wsh[FA_ROWS];
  int blk = blockIdx.x, tid = threadIdx.x;

  if (blk == 0 && tid < 16) ctr[tid] = 0;

  int bc = blk >> 6, ch = blk & 63;
  int s0 = ch * FA_ROWS;
  #pragma unroll
  for (int i = 0; i < 9; i++){                  // stage 12 rows (halo +-2)
    int f = i * 256 + tid;
    int row = f / 192, c4 = f % 192;
    int gs = s0 - 2 + row;
    if (gs >= 0 && gs < S)
      *(f32x4*)&smemF[row * HP + c4 * 4] =
        *(const f32x4*)&tok[((size_t)bc * S + gs) * H + c4 * 4];
  }
  __syncthreads();
  if (tid < 192){                               // scores: 12 rows x 16 lanes
    int r = tid >> 4, e = tid & 15;
    int gs = s0 - 2 + r;
    const f32x4* wq = (const f32x4*)w_tok;
    f32x4 a4 = {0.f, 0.f, 0.f, 0.f};
    #pragma unroll
    for (int i = 0; i < 12; i++){
      int k = e + 16 * i;
      a4 += *(const f32x4*)&smemF[r * HP + k * 4] * wq[k];
    }
    float acc = hsum(a4);
    acc += __shfl_xor(acc, 1, 64);
    acc += __shfl_xor(acc, 2, 64);
    acc += __shfl_xor(acc, 4, 64);
    acc += __shfl_xor(acc, 8, 64);
    if (e == 0) scr[r] = (gs >= 0 && gs < S) ? sigm(acc + b_tok[0]) : 0.f;
  }
  __syncthreads();
  if (tid < FA_ROWS){
    float w = (scr[tid] + scr[tid+1] + scr[tid+2] + scr[tid+3] + scr[tid+4]) * 0.2f;
    wsh[tid] = w;
    win_out[(size_t)bc * S + s0 + tid] = w;
  }
  __syncthreads();
  if (tid < 192){                               // weighted partial over 8 rows
    f32x4 acc = {0.f, 0.f, 0.f, 0.f};
    #pragma unroll
    for (int i = 0; i < FA_ROWS; i++){
      float w = wsh[i];
      f32x4 a = *(const f32x4*)&smemF[(i + 2) * HP + tid * 4];
      acc += a * w;
    }
    *(f32x4*)&wpart[((size_t)ch * BC + bc) * H + tid * 4] = acc;
  }
}

// ================= Kernel 2: xgate fwd+bwd ===================================
__global__ __launch_bounds__(256) void k_xg(
    const float* __restrict__ tok,
    const float* __restrict__ w_ih_f, const float* __restrict__ b_ih_f, const float* __restrict__ b_hh_f,
    const float* __restrict__ w_ih_b, const float* __restrict__ b_ih_b, const float* __restrict__ b_hh_b,
    float* __restrict__ xg, float* __restrict__ gbwd){
  __shared__ float smemX[8 * HP];                // 24704 B
  int blk = blockIdx.x, tid = threadIdx.x;
  bool fwd = (blk < XF_BLK);
  int rblk, base_bc = 0;
  const float *w, *bi, *bh; float* outp;
  if (fwd){ rblk = blk / 10; base_bc = (blk % 10) * 8; w = w_ih_f; bi = b_ih_f; bh = b_hh_f; outp = xg; }
  else    { rblk = blk - XF_BLK;                      w = w_ih_b; bi = b_ih_b; bh = b_hh_b; outp = gbwd; }
  #pragma unroll
  for (int i = 0; i < 6; i++){                   // stage 8 tok rows
    int f = i * 256 + tid;
    int bl = f / 192, c4 = f % 192;
    size_t bc = fwd ? (size_t)(base_bc + bl) : ((size_t)bl * NC + NC - 1);
    *(f32x4*)&smemX[bl * HP + c4 * 4] = *(const f32x4*)&tok[bc * (size_t)S * H + c4 * 4];
  }
  __syncthreads();
  {
    int bl = tid & 7, rl = tid >> 3;
    int r = rblk * 32 + rl;
    const f32x4* wr = (const f32x4*)(w + (size_t)r * H);
    f32x4 a4 = {0.f, 0.f, 0.f, 0.f};
    #pragma unroll 8
    for (int k = 0; k < 192; k++)
      a4 += *(const f32x4*)&smemX[bl * HP + k * 4] * wr[k];
    int ob = fwd ? (base_bc + bl) : bl;
    outp[(size_t)ob * G4 + r] = hsum(a4) + bi[r] + bh[r];
  }
}

// ================= Kernel 3: cooperative back, w_hh in LDS ===================
struct BackArgs {
  const float *w_sum, *b_sum, *w_proj, *b_proj;
  const float *w_hh, *xg, *gbwd, *w_cls, *b_cls, *wpart;
  float *wmean, *s1, *summ_out, *hx, *cls_out;
  unsigned *ctr;
};

__global__ __launch_bounds__(256) void k_back(BackArgs A){
  __shared__ float smem[37696];                  // 150.8 KB total
  float* w_sh  = smem;                           // [32][772] w_hh rows (98.8 KB)
  float* h_sh  = smem + 24704;                   // [8][772]
  float* a_sh  = smem + 30880;                   // [8][772]
  float* c_sh  = smem + 37056;                   // [64]
  float* g_sh  = smem + 37120;                   // [8jl][4g][8b] = 256
  float* pg_sh = smem + 37376;                   // [64][5] = 320
  int tid = threadIdx.x, lane = tid & 63, wv = tid >> 6, blkx = blockIdx.x;

  auto gbar = [&](int slot){
    asm volatile("s_waitcnt vmcnt(0)" ::: "memory");
    __syncthreads();
    if (tid == 0){
      __hip_atomic_fetch_add(&A.ctr[slot], 1u, __ATOMIC_RELAXED, __HIP_MEMORY_SCOPE_AGENT);
      while (__hip_atomic_load(&A.ctr[slot], __ATOMIC_RELAXED, __HIP_MEMORY_SCOPE_AGENT) < (unsigned)NBACK)
        __builtin_amdgcn_s_sleep(1);
    }
    __syncthreads();
  };

  auto stage6 = [&](float* dst, const float* src){
    const f32x4* s4 = (const f32x4*)src;
    f32x4 d[6];
    coh_load6(d, s4 + tid, s4 + 256 + tid, s4 + 512 + tid,
                 s4 + 768 + tid, s4 + 1024 + tid, s4 + 1280 + tid);
    #pragma unroll
    for (int i = 0; i < 6; i++){
      int f = i * 256 + tid, b = f / 192, j4 = f % 192;
      *(f32x4*)&dst[b * HP + j4 * 4] = d[i];
    }
  };

  // ---- preload w_hh rows (once, plain cached loads): lr = jl*4 + g ----
  #pragma unroll
  for (int i = 0; i < 24; i++){
    int f = i * 256 + tid;          // 0..6143 f32x4 units
    int lr = f / 192, k = f % 192;
    int g = lr & 3, jl = lr >> 2;
    int r = g * H + blkx * 8 + jl;
    *(f32x4*)&w_sh[lr * HP + k * 4] = *(const f32x4*)&A.w_hh[(size_t)r * H + k * 4];
  }

  // step t: thread = (lr = tid>>3, b = tid&7); w from LDS, conflict-free
  auto do_step = [&](int t){
    int b = tid & 7, lr = tid >> 3;
    int g = lr & 3, jl = lr >> 2;
    int r = g * H + blkx * 8 + jl;
    float xgv = A.xg[((size_t)b * NC + t) * G4 + r];
    const f32x4* wr = (const f32x4*)&w_sh[lr * HP];
    const f32x4* hb = (const f32x4*)&h_sh[b * HP];
    f32x4 a4 = {0.f, 0.f, 0.f, 0.f};
    #pragma unroll 8
    for (int k = 0; k < 192; k++)
      a4 += wr[k] * hb[k];
    g_sh[jl * 32 + g * 8 + b] = hsum(a4) + xgv;
    __syncthreads();
    if (tid < 64){
      int jj = tid >> 3, b2 = tid & 7;
      float gi = g_sh[jj*32 + b2],      gf = g_sh[jj*32 + 8 + b2];
      float gg = g_sh[jj*32 + 16 + b2], go = g_sh[jj*32 + 24 + b2];
      float c = sigm(gf) * c_sh[tid] + sigm(gi) * tanh_fast(gg);
      c_sh[tid] = c;
      coh_store1(&A.hx[(t & 1) * (Bsz*H) + b2 * H + blkx * 8 + jj],
                 sigm(go) * tanh_fast(c));
    }
  };

  // ---- P0: wmean (parallel partials over 64 chunks) + LSTM init ----
  {
    int out = tid >> 2, ps = tid & 3;            // 64 outputs x 4 p-slices
    int idx = blkx * 64 + out;
    int b = idx / H, hh = idx % H;
    float acc = 0.f;
    for (int p = ps * 16; p < ps * 16 + 16; p++)
      #pragma unroll
      for (int c = 0; c < NC; c++)
        acc += A.wpart[((size_t)p * BC + b * NC + c) * H + hh];
    pg_sh[out * 5 + ps] = acc;
  }
  __syncthreads();
  if (tid < 64){
    float acc = pg_sh[tid*5] + pg_sh[tid*5+1] + pg_sh[tid*5+2] + pg_sh[tid*5+3];
    coh_store1(&A.wmean[blkx * 64 + tid], acc * 0.1f);
    int jl = tid >> 3, b2 = tid & 7, j = blkx * 8 + jl;
    const float* gp = A.xg + (size_t)(b2 * NC) * G4;
    float c = sigm(gp[j]) * tanh_fast(gp[2*H + j]);
    c_sh[tid] = c;
    coh_store1(&A.hx[b2 * H + j], sigm(gp[3*H + j]) * tanh_fast(c));
  }
  gbar(0);

  // ---- P1: s1 = wmean @ w_sum.T  ||  step1 ----
  stage6(a_sh, A.wmean);
  stage6(h_sh, A.hx);            // h1 (buf 0)
  __syncthreads();
  {
    int out = tid >> 2, q = tid & 3;
    int ol = out >> 3, b = out & 7;
    int o = blkx * 8 + ol;
    const f32x4* wq = (const f32x4*)(A.w_sum + (size_t)o * H) + q * 48;
    f32x4 a4 = {0.f, 0.f, 0.f, 0.f};
    #pragma unroll 8
    for (int k = 0; k < 48; k++)
      a4 += *(const f32x4*)&a_sh[b * HP + (q * 48 + k) * 4] * wq[k];
    float acc = hsum(a4);
    acc += __shfl_xor(acc, 1, 64);
    acc += __shfl_xor(acc, 2, 64);
    if (q == 0) coh_store1(&A.s1[(size_t)b * H + o], acc + A.b_sum[o]);
  }
  do_step(1);
  gbar(1);

  // ---- P2: summ = s1 @ w_proj.T  ||  step2 ----
  stage6(a_sh, A.s1);
  stage6(h_sh, A.hx + Bsz*H);    // h2 (buf 1)
  __syncthreads();
  {
    int out = tid >> 1, hf = tid & 1;
    int ol = out >> 3, b = out & 7;
    int o = blkx * 16 + ol;
    const f32x4* wq = (const f32x4*)(A.w_proj + (size_t)o * H) + hf * 96;
    f32x4 a4 = {0.f, 0.f, 0.f, 0.f};
    #pragma unroll 8
    for (int k = 0; k < 96; k++)
      a4 += *(const f32x4*)&a_sh[b * HP + (hf * 96 + k) * 4] * wq[k];
    float acc = hsum(a4);
    acc += __shfl_xor(acc, 1, 64);
    if (hf == 0) coh_store1(&A.summ_out[(size_t)b * H2 + o], acc + A.b_proj[o]);
  }
  do_step(2);
  gbar(2);

  // ---- steps 3..9 ----
  for (int t = 3; t <= 9; t++){
    stage6(h_sh, A.hx + ((t - 1) & 1) * (Bsz*H));
    __syncthreads();
    do_step(t);
    gbar(t);
  }

  // ---- fincls on block 0: comb = [h10|hb] + summ ; cls ----
  if (blkx == 0){
    float* comb = smem;                          // 12288 floats (reuses w_sh)
    {
      f32x4 d[6];
      const f32x4* h4 = (const f32x4*)(A.hx + Bsz*H);   // h10 (buf 1)
      coh_load6(d, h4 + tid, h4 + 256 + tid, h4 + 512 + tid,
                   h4 + 768 + tid, h4 + 1024 + tid, h4 + 1280 + tid);
      #pragma unroll
      for (int i = 0; i < 6; i++){
        int f = i * 256 + tid, b = f / 192, e = (f % 192) * 4;
        *(f32x4*)&comb[b * H2 + e] = d[i];
      }
      #pragma unroll
      for (int u = 0; u < 6; u++){               // hb from gbwd (plain loads)
        int f = u * 256 + tid;
        int b = f / 192, e = (f % 192) * 4;
        f32x4 gi = *(const f32x4*)&A.gbwd[(size_t)b * G4 + e];
        f32x4 gg = *(const f32x4*)&A.gbwd[(size_t)b * G4 + 2*H + e];
        f32x4 go = *(const f32x4*)&A.gbwd[(size_t)b * G4 + 3*H + e];
        f32x4 hb;
        hb.x = sigm(go.x) * tanh_fast(sigm(gi.x) * tanh_fast(gg.x));
        hb.y = sigm(go.y) * tanh_fast(sigm(gi.y) * tanh_fast(gg.y));
        hb.z = sigm(go.z) * tanh_fast(sigm(gi.z) * tanh_fast(gg.z));
        hb.w = sigm(go.w) * tanh_fast(sigm(gi.w) * tanh_fast(gg.w));
        *(f32x4*)&comb[b * H2 + H + e] = hb;
      }
    }
    __syncthreads();
    {
      f32x4 d[6];
      const f32x4* s4 = (const f32x4*)A.summ_out;
      coh_load6(d, s4 + tid, s4 + 256 + tid, s4 + 512 + tid,
                   s4 + 768 + tid, s4 + 1024 + tid, s4 + 1280 + tid);
      #pragma unroll
      for (int i = 0; i < 6; i++) *(f32x4*)&comb[(i * 256 + tid) * 4] += d[i];
      coh_load6(d, s4 + 1536 + tid, s4 + 1792 + tid, s4 + 2048 + tid,
                   s4 + 2304 + tid, s4 + 2560 + tid, s4 + 2816 + tid);
      #pragma unroll
      for (int i = 0; i < 6; i++) *(f32x4*)&comb[(1536 + i * 256 + tid) * 4] += d[i];
    }
    __syncthreads();
    for (int b = wv; b < Bsz; b += 4){
      const f32x4* c4 = (const f32x4*)&comb[b * H2];
      const f32x4* wc = (const f32x4*)A.w_cls;
      f32x4 a4 = {0.f, 0.f, 0.f, 0.f};
      #pragma unroll
      for (int k = 0; k < 6; k++)
        a4 += c4[lane + 64*k] * wc[lane + 64*k];
      float acc = wred(hsum(a4));
      if (lane == 0) A.cls_out[b] = sigm(acc + A.b_cls[0]);
    }
  }
}

} // namespace

extern "C" void kernel_launch(void* const* d_in, const int* in_sizes, int n_in,
                              void* d_out, int out_size, void* d_ws, size_t ws_size,
                              hipStream_t stream) {
  const float* tok    = (const float*)d_in[0];
  const float* w_tok  = (const float*)d_in[1];
  const float* b_tok  = (const float*)d_in[2];
  const float* w_sum  = (const float*)d_in[3];
  const float* b_sum  = (const float*)d_in[4];
  const float* w_proj = (const float*)d_in[5];
  const float* b_proj = (const float*)d_in[6];
  const float* w_ih_f = (const float*)d_in[7];
  const float* w_hh_f = (const float*)d_in[8];
  const float* b_ih_f = (const float*)d_in[9];
  const float* b_hh_f = (const float*)d_in[10];
  const float* w_ih_b = (const float*)d_in[11];
  const float* b_ih_b = (const float*)d_in[13];
  const float* b_hh_b = (const float*)d_in[14];
  const float* w_cls  = (const float*)d_in[15];
  const float* b_cls  = (const float*)d_in[16];

  float* out      = (float*)d_out;
  float* cls_out  = out;
  float* win_out  = out + 8;
  float* summ_out = out + 8 + BC * S;

  float* ws     = (float*)d_ws;
  float* wpart  = ws;                              // 64*80*768
  float* wmean  = wpart + (size_t)FA_CH * BC * H;  // 6144
  float* s1     = wmean + Bsz * H;                 // 6144
  float* xg     = s1 + Bsz * H;                    // 245760
  float* gbwd   = xg + (size_t)BC * G4;            // 24576
  float* hx     = gbwd + (size_t)Bsz * G4;         // 12288 (2 bufs)
  unsigned* ctr = (unsigned*)(hx + 2 * Bsz * H);   // 16

  k_fa<<<FA_BLK, 256, 0, stream>>>(tok, w_tok, b_tok, win_out, wpart, ctr);
  k_xg<<<XG_BLK, 256, 0, stream>>>(tok, w_ih_f, b_ih_f, b_hh_f,
                                   w_ih_b, b_ih_b, b_hh_b, xg, gbwd);

  BackArgs ba;
  ba.w_sum = w_sum; ba.b_sum = b_sum; ba.w_proj = w_proj; ba.b_proj = b_proj;
  ba.w_hh = w_hh_f; ba.xg = xg; ba.gbwd = gbwd; ba.w_cls = w_cls; ba.b_cls = b_cls;
  ba.wpart = wpart; ba.wmean = wmean; ba.s1 = s1; ba.summ_out = summ_out;
  ba.hx = hx; ba.cls_out = cls_out; ba.ctr = ctr;

  void* params[] = { &ba };
  hipLaunchCooperativeKernel(reinterpret_cast<void*>(k_back),
                             dim3(NBACK), dim3(256), params, 0, stream);
}

// Round 12
// 179.530 us; speedup vs baseline: 1.4414x; 1.0313x over previous
//
#include <hip/hip_runtime.h>

namespace {

constexpr int Bsz = 8, NC = 10, BC = 80, S = 512, H = 768, G4 = 3072, H2 = 1536;
constexpr int FA_CH = 64, FA_ROWS = 8, FA_STG = 12;   // 8-row tiles + 4 halo
constexpr int FA_BLK = BC * FA_CH;      // 5120
constexpr int XF_BLK = 960, XB_BLK = 96;
constexpr int FRONT_BLK = FA_BLK + XF_BLK + XB_BLK;   // 6176
constexpr int NBACK = 96;               // cooperative back blocks
constexpr int HP = 772;                 // LDS row pad (dwords)
constexpr int CTR_N = 1600;             // 10 slots x 160 uints (8 grp lines + global)

typedef float f32x4 __attribute__((ext_vector_type(4)));

__device__ __forceinline__ float sigm(float x){ return 1.0f/(1.0f + __expf(-x)); }
__device__ __forceinline__ float tanh_fast(float x){ return 1.0f - 2.0f/(__expf(2.0f*x) + 1.0f); }
__device__ __forceinline__ float hsum(f32x4 a){ return (a.x+a.y)+(a.z+a.w); }
__device__ __forceinline__ float wred(float v){
  #pragma unroll
  for (int m = 32; m; m >>= 1) v += __shfl_xor(v, m, 64);
  return v;
}

// ---- coherent (cross-XCD via MALL) access: sc0 sc1 (R6-proven) ----
__device__ __forceinline__ void coh_load6(f32x4 (&d)[6],
    const f32x4* p0, const f32x4* p1, const f32x4* p2,
    const f32x4* p3, const f32x4* p4, const f32x4* p5){
  asm volatile(
    "global_load_dwordx4 %0, %6, off sc0 sc1\n\t"
    "global_load_dwordx4 %1, %7, off sc0 sc1\n\t"
    "global_load_dwordx4 %2, %8, off sc0 sc1\n\t"
    "global_load_dwordx4 %3, %9, off sc0 sc1\n\t"
    "global_load_dwordx4 %4, %10, off sc0 sc1\n\t"
    "global_load_dwordx4 %5, %11, off sc0 sc1\n\t"
    "s_waitcnt vmcnt(0)"
    : "=&v"(d[0]), "=&v"(d[1]), "=&v"(d[2]), "=&v"(d[3]), "=&v"(d[4]), "=&v"(d[5])
    : "v"(p0), "v"(p1), "v"(p2), "v"(p3), "v"(p4), "v"(p5)
    : "memory");
}
__device__ __forceinline__ void coh_store1(float* p, float v){
  asm volatile("global_store_dword %0, %1, off sc0 sc1" :: "v"(p), "v"(v) : "memory");
}

// ================= Kernel 1: fusedA || xgate (merged, 37 KB LDS) =============
__global__ __launch_bounds__(256) void k_front(
    const float* __restrict__ tok, const float* __restrict__ w_tok,
    const float* __restrict__ b_tok, float* __restrict__ win_out,
    float* __restrict__ wpart,
    const float* __restrict__ w_ih_f, const float* __restrict__ b_ih_f, const float* __restrict__ b_hh_f,
    const float* __restrict__ w_ih_b, const float* __restrict__ b_ih_b, const float* __restrict__ b_hh_b,
    float* __restrict__ xg, float* __restrict__ gbwd, unsigned* __restrict__ ctr){
  __shared__ float smemF[FA_STG * HP];   // 37056 B
  __shared__ float scr[FA_STG];
  __shared__ float wsh[FA_ROWS];
  int blk = blockIdx.x, tid = threadIdx.x;

  if (blk == 0) for (int i = tid; i < CTR_N; i += 256) ctr[i] = 0;

  if (blk < FA_BLK){
    // ---------- fusedA (R11-verbatim) ----------
    int bc = blk >> 6, ch = blk & 63;
    int s0 = ch * FA_ROWS;
    #pragma unroll
    for (int i = 0; i < 9; i++){                  // stage 12 rows (halo +-2)
      int f = i * 256 + tid;
      int row = f / 192, c4 = f % 192;
      int gs = s0 - 2 + row;
      if (gs >= 0 && gs < S)
        *(f32x4*)&smemF[row * HP + c4 * 4] =
          *(const f32x4*)&tok[((size_t)bc * S + gs) * H + c4 * 4];
    }
    __syncthreads();
    if (tid < 192){                               // scores: 12 rows x 16 lanes
      int r = tid >> 4, e = tid & 15;
      int gs = s0 - 2 + r;
      const f32x4* wq = (const f32x4*)w_tok;
      f32x4 a4 = {0.f, 0.f, 0.f, 0.f};
      #pragma unroll
      for (int i = 0; i < 12; i++){
        int k = e + 16 * i;
        a4 += *(const f32x4*)&smemF[r * HP + k * 4] * wq[k];
      }
      float acc = hsum(a4);
      acc += __shfl_xor(acc, 1, 64);
      acc += __shfl_xor(acc, 2, 64);
      acc += __shfl_xor(acc, 4, 64);
      acc += __shfl_xor(acc, 8, 64);
      if (e == 0) scr[r] = (gs >= 0 && gs < S) ? sigm(acc + b_tok[0]) : 0.f;
    }
    __syncthreads();
    if (tid < FA_ROWS){
      float w = (scr[tid] + scr[tid+1] + scr[tid+2] + scr[tid+3] + scr[tid+4]) * 0.2f;
      wsh[tid] = w;
      win_out[(size_t)bc * S + s0 + tid] = w;
    }
    __syncthreads();
    if (tid < 192){                               // weighted partial over 8 rows
      f32x4 acc = {0.f, 0.f, 0.f, 0.f};
      #pragma unroll
      for (int i = 0; i < FA_ROWS; i++){
        float w = wsh[i];
        f32x4 a = *(const f32x4*)&smemF[(i + 2) * HP + tid * 4];
        acc += a * w;
      }
      *(f32x4*)&wpart[((size_t)ch * BC + bc) * H + tid * 4] = acc;
    }
    return;
  }

  // ---------- xgate (R11-verbatim, uses first 8 rows of smemF) ----------
  int xb = blk - FA_BLK;
  bool fwd = (xb < XF_BLK);
  int rblk, base_bc = 0;
  const float *w, *bi, *bh; float* outp;
  if (fwd){ rblk = xb / 10; base_bc = (xb % 10) * 8; w = w_ih_f; bi = b_ih_f; bh = b_hh_f; outp = xg; }
  else    { rblk = xb - XF_BLK;                      w = w_ih_b; bi = b_ih_b; bh = b_hh_b; outp = gbwd; }
  #pragma unroll
  for (int i = 0; i < 6; i++){                   // stage 8 tok rows
    int f = i * 256 + tid;
    int bl = f / 192, c4 = f % 192;
    size_t bc = fwd ? (size_t)(base_bc + bl) : ((size_t)bl * NC + NC - 1);
    *(f32x4*)&smemF[bl * HP + c4 * 4] = *(const f32x4*)&tok[bc * (size_t)S * H + c4 * 4];
  }
  __syncthreads();
  {
    int bl = tid & 7, rl = tid >> 3;
    int r = rblk * 32 + rl;
    const f32x4* wr = (const f32x4*)(w + (size_t)r * H);
    f32x4 a4 = {0.f, 0.f, 0.f, 0.f};
    #pragma unroll 8
    for (int k = 0; k < 192; k++)
      a4 += *(const f32x4*)&smemF[bl * HP + k * 4] * wr[k];
    int ob = fwd ? (base_bc + bl) : bl;
    outp[(size_t)ob * G4 + r] = hsum(a4) + bi[r] + bh[r];
  }
}

// ================= Kernel 2: cooperative back, tree barrier ==================
struct BackArgs {
  const float *w_sum, *b_sum, *w_proj, *b_proj;
  const float *w_hh, *xg, *gbwd, *w_cls, *b_cls, *wpart;
  float *wmean, *s1, *summ_out, *hx, *cls_out;
  unsigned *ctr;
};

__global__ __launch_bounds__(256) void k_back(BackArgs A){
  __shared__ float smem[37696];                  // 150.8 KB total
  float* w_sh  = smem;                           // [32][772] w_hh rows (98.8 KB)
  float* h_sh  = smem + 24704;                   // [8][772]
  float* a_sh  = smem + 30880;                   // [8][772]
  float* c_sh  = smem + 37056;                   // [64]
  float* g_sh  = smem + 37120;                   // [8jl][4g][8b] = 256
  float* pg_sh = smem + 37376;                   // [64][5] = 320
  int tid = threadIdx.x, lane = tid & 63, wv = tid >> 6, blkx = blockIdx.x;

  // tree barrier: 8 group lines (12 arrivals each) + 1 global line
  auto gbar = [&](int slot){
    asm volatile("s_waitcnt vmcnt(0)" ::: "memory");
    __syncthreads();
    if (tid == 0){
      unsigned* base = A.ctr + slot * 160;
      int grp = blkx / 12;
      unsigned old = __hip_atomic_fetch_add(&base[grp * 16], 1u,
                        __ATOMIC_RELAXED, __HIP_MEMORY_SCOPE_AGENT);
      if (old == 11u)
        __hip_atomic_fetch_add(&base[128], 1u, __ATOMIC_RELAXED, __HIP_MEMORY_SCOPE_AGENT);
      while (__hip_atomic_load(&base[128], __ATOMIC_RELAXED, __HIP_MEMORY_SCOPE_AGENT) < 8u)
        __builtin_amdgcn_s_sleep(1);
    }
    __syncthreads();
  };

  auto stage6 = [&](float* dst, const float* src){
    const f32x4* s4 = (const f32x4*)src;
    f32x4 d[6];
    coh_load6(d, s4 + tid, s4 + 256 + tid, s4 + 512 + tid,
                 s4 + 768 + tid, s4 + 1024 + tid, s4 + 1280 + tid);
    #pragma unroll
    for (int i = 0; i < 6; i++){
      int f = i * 256 + tid, b = f / 192, j4 = f % 192;
      *(f32x4*)&dst[b * HP + j4 * 4] = d[i];
    }
  };

  // ---- preload w_hh rows (once): lr = jl*4 + g ----
  #pragma unroll
  for (int i = 0; i < 24; i++){
    int f = i * 256 + tid;
    int lr = f / 192, k = f % 192;
    int g = lr & 3, jl = lr >> 2;
    int r = g * H + blkx * 8 + jl;
    *(f32x4*)&w_sh[lr * HP + k * 4] = *(const f32x4*)&A.w_hh[(size_t)r * H + k * 4];
  }

  // hoisted step mapping (thread = (lr = tid>>3, b = tid&7))
  int sb = tid & 7, slr = tid >> 3;
  int sjl = slr >> 2, sg = slr & 3;
  int sr = sg * H + blkx * 8 + sjl;
  size_t xgrow = (size_t)sb * NC;

  // step t with prefetched xg value
  auto do_step = [&](int t, float xgv){
    const f32x4* wr = (const f32x4*)&w_sh[slr * HP];
    const f32x4* hb = (const f32x4*)&h_sh[sb * HP];
    f32x4 a4 = {0.f, 0.f, 0.f, 0.f};
    #pragma unroll 8
    for (int k = 0; k < 192; k++)
      a4 += wr[k] * hb[k];
    g_sh[sjl * 32 + sg * 8 + sb] = hsum(a4) + xgv;
    __syncthreads();
    if (tid < 64){
      int jj = tid >> 3, b2 = tid & 7;
      float gi = g_sh[jj*32 + b2],      gf = g_sh[jj*32 + 8 + b2];
      float gg = g_sh[jj*32 + 16 + b2], go = g_sh[jj*32 + 24 + b2];
      float c = sigm(gf) * c_sh[tid] + sigm(gi) * tanh_fast(gg);
      c_sh[tid] = c;
      coh_store1(&A.hx[(t & 1) * (Bsz*H) + b2 * H + blkx * 8 + jj],
                 sigm(go) * tanh_fast(c));
    }
  };

  // ---- P0: wmean (parallel partials over 64 chunks) + LSTM init ----
  {
    int out = tid >> 2, ps = tid & 3;            // 64 outputs x 4 p-slices
    int idx = blkx * 64 + out;
    int b = idx / H, hh = idx % H;
    float acc = 0.f;
    for (int p = ps * 16; p < ps * 16 + 16; p++)
      #pragma unroll
      for (int c = 0; c < NC; c++)
        acc += A.wpart[((size_t)p * BC + b * NC + c) * H + hh];
    pg_sh[out * 5 + ps] = acc;
  }
  __syncthreads();
  if (tid < 64){
    float acc = pg_sh[tid*5] + pg_sh[tid*5+1] + pg_sh[tid*5+2] + pg_sh[tid*5+3];
    coh_store1(&A.wmean[blkx * 64 + tid], acc * 0.1f);
    int jl = tid >> 3, b2 = tid & 7, j = blkx * 8 + jl;
    const float* gp = A.xg + (size_t)(b2 * NC) * G4;
    float c = sigm(gp[j]) * tanh_fast(gp[2*H + j]);
    c_sh[tid] = c;
    coh_store1(&A.hx[b2 * H + j], sigm(gp[3*H + j]) * tanh_fast(c));
  }
  float xgv = A.xg[(xgrow + 1) * G4 + sr];       // prefetch step1
  gbar(0);

  // ---- P1: s1 = wmean @ w_sum.T  ||  step1 ----
  stage6(a_sh, A.wmean);
  stage6(h_sh, A.hx);            // h1 (buf 0)
  __syncthreads();
  {
    int out = tid >> 2, q = tid & 3;
    int ol = out >> 3, b = out & 7;
    int o = blkx * 8 + ol;
    const f32x4* wq = (const f32x4*)(A.w_sum + (size_t)o * H) + q * 48;
    f32x4 a4 = {0.f, 0.f, 0.f, 0.f};
    #pragma unroll 8
    for (int k = 0; k < 48; k++)
      a4 += *(const f32x4*)&a_sh[b * HP + (q * 48 + k) * 4] * wq[k];
    float acc = hsum(a4);
    acc += __shfl_xor(acc, 1, 64);
    acc += __shfl_xor(acc, 2, 64);
    if (q == 0) coh_store1(&A.s1[(size_t)b * H + o], acc + A.b_sum[o]);
  }
  do_step(1, xgv);
  xgv = A.xg[(xgrow + 2) * G4 + sr];             // prefetch step2
  gbar(1);

  // ---- P2: summ = s1 @ w_proj.T  ||  step2 ----
  stage6(a_sh, A.s1);
  stage6(h_sh, A.hx + Bsz*H);    // h2 (buf 1)
  __syncthreads();
  {
    int out = tid >> 1, hf = tid & 1;
    int ol = out >> 3, b = out & 7;
    int o = blkx * 16 + ol;
    const f32x4* wq = (const f32x4*)(A.w_proj + (size_t)o * H) + hf * 96;
    f32x4 a4 = {0.f, 0.f, 0.f, 0.f};
    #pragma unroll 8
    for (int k = 0; k < 96; k++)
      a4 += *(const f32x4*)&a_sh[b * HP + (hf * 96 + k) * 4] * wq[k];
    float acc = hsum(a4);
    acc += __shfl_xor(acc, 1, 64);
    if (hf == 0) coh_store1(&A.summ_out[(size_t)b * H2 + o], acc + A.b_proj[o]);
  }
  do_step(2, xgv);
  xgv = A.xg[(xgrow + 3) * G4 + sr];             // prefetch step3
  gbar(2);

  // ---- steps 3..9 ----
  for (int t = 3; t <= 9; t++){
    stage6(h_sh, A.hx + ((t - 1) & 1) * (Bsz*H));
    __syncthreads();
    do_step(t, xgv);
    if (t < 9) xgv = A.xg[(xgrow + t + 1) * G4 + sr];
    gbar(t);
  }

  // ---- fincls on block 0: comb = [h10|hb] + summ ; cls ----
  if (blkx == 0){
    float* comb = smem;                          // 12288 floats (reuses w_sh)
    {
      f32x4 d[6];
      const f32x4* h4 = (const f32x4*)(A.hx + Bsz*H);   // h10 (buf 1)
      coh_load6(d, h4 + tid, h4 + 256 + tid, h4 + 512 + tid,
                   h4 + 768 + tid, h4 + 1024 + tid, h4 + 1280 + tid);
      #pragma unroll
      for (int i = 0; i < 6; i++){
        int f = i * 256 + tid, b = f / 192, e = (f % 192) * 4;
        *(f32x4*)&comb[b * H2 + e] = d[i];
      }
      #pragma unroll
      for (int u = 0; u < 6; u++){               // hb from gbwd (plain loads)
        int f = u * 256 + tid;
        int b = f / 192, e = (f % 192) * 4;
        f32x4 gi = *(const f32x4*)&A.gbwd[(size_t)b * G4 + e];
        f32x4 gg = *(const f32x4*)&A.gbwd[(size_t)b * G4 + 2*H + e];
        f32x4 go = *(const f32x4*)&A.gbwd[(size_t)b * G4 + 3*H + e];
        f32x4 hb;
        hb.x = sigm(go.x) * tanh_fast(sigm(gi.x) * tanh_fast(gg.x));
        hb.y = sigm(go.y) * tanh_fast(sigm(gi.y) * tanh_fast(gg.y));
        hb.z = sigm(go.z) * tanh_fast(sigm(gi.z) * tanh_fast(gg.z));
        hb.w = sigm(go.w) * tanh_fast(sigm(gi.w) * tanh_fast(gg.w));
        *(f32x4*)&comb[b * H2 + H + e] = hb;
      }
    }
    __syncthreads();
    {
      f32x4 d[6];
      const f32x4* s4 = (const f32x4*)A.summ_out;
      coh_load6(d, s4 + tid, s4 + 256 + tid, s4 + 512 + tid,
                   s4 + 768 + tid, s4 + 1024 + tid, s4 + 1280 + tid);
      #pragma unroll
      for (int i = 0; i < 6; i++) *(f32x4*)&comb[(i * 256 + tid) * 4] += d[i];
      coh_load6(d, s4 + 1536 + tid, s4 + 1792 + tid, s4 + 2048 + tid,
                   s4 + 2304 + tid, s4 + 2560 + tid, s4 + 2816 + tid);
      #pragma unroll
      for (int i = 0; i < 6; i++) *(f32x4*)&comb[(1536 + i * 256 + tid) * 4] += d[i];
    }
    __syncthreads();
    for (int b = wv; b < Bsz; b += 4){
      const f32x4* c4 = (const f32x4*)&comb[b * H2];
      const f32x4* wc = (const f32x4*)A.w_cls;
      f32x4 a4 = {0.f, 0.f, 0.f, 0.f};
      #pragma unroll
      for (int k = 0; k < 6; k++)
        a4 += c4[lane + 64*k] * wc[lane + 64*k];
      float acc = wred(hsum(a4));
      if (lane == 0) A.cls_out[b] = sigm(acc + A.b_cls[0]);
    }
  }
}

} // namespace

extern "C" void kernel_launch(void* const* d_in, const int* in_sizes, int n_in,
                              void* d_out, int out_size, void* d_ws, size_t ws_size,
                              hipStream_t stream) {
  const float* tok    = (const float*)d_in[0];
  const float* w_tok  = (const float*)d_in[1];
  const float* b_tok  = (const float*)d_in[2];
  const float* w_sum  = (const float*)d_in[3];
  const float* b_sum  = (const float*)d_in[4];
  const float* w_proj = (const float*)d_in[5];
  const float* b_proj = (const float*)d_in[6];
  const float* w_ih_f = (const float*)d_in[7];
  const float* w_hh_f = (const float*)d_in[8];
  const float* b_ih_f = (const float*)d_in[9];
  const float* b_hh_f = (const float*)d_in[10];
  const float* w_ih_b = (const float*)d_in[11];
  const float* b_ih_b = (const float*)d_in[13];
  const float* b_hh_b = (const float*)d_in[14];
  const float* w_cls  = (const float*)d_in[15];
  const float* b_cls  = (const float*)d_in[16];

  float* out      = (float*)d_out;
  float* cls_out  = out;
  float* win_out  = out + 8;
  float* summ_out = out + 8 + BC * S;

  float* ws     = (float*)d_ws;
  float* wpart  = ws;                              // 64*80*768
  float* wmean  = wpart + (size_t)FA_CH * BC * H;  // 6144
  float* s1     = wmean + Bsz * H;                 // 6144
  float* xg     = s1 + Bsz * H;                    // 245760
  float* gbwd   = xg + (size_t)BC * G4;            // 24576
  float* hx     = gbwd + (size_t)Bsz * G4;         // 12288 (2 bufs)
  unsigned* ctr = (unsigned*)(hx + 2 * Bsz * H);   // 1600 uints

  k_front<<<FRONT_BLK, 256, 0, stream>>>(tok, w_tok, b_tok, win_out, wpart,
                                         w_ih_f, b_ih_f, b_hh_f,
                                         w_ih_b, b_ih_b, b_hh_b, xg, gbwd, ctr);

  BackArgs ba;
  ba.w_sum = w_sum; ba.b_sum = b_sum; ba.w_proj = w_proj; ba.b_proj = b_proj;
  ba.w_hh = w_hh_f; ba.xg = xg; ba.gbwd = gbwd; ba.w_cls = w_cls; ba.b_cls = b_cls;
  ba.wpart = wpart; ba.wmean = wmean; ba.s1 = s1; ba.summ_out = summ_out;
  ba.hx = hx; ba.cls_out = cls_out; ba.ctr = ctr;

  void* params[] = { &ba };
  hipLaunchCooperativeKernel(reinterpret_cast<void*>(k_back),
                             dim3(NBACK), dim3(256), params, 0, stream);
}

// Round 13
// 176.071 us; speedup vs baseline: 1.4697x; 1.0196x over previous
//
#include <hip/hip_runtime.h>

namespace {

constexpr int Bsz = 8, NC = 10, BC = 80, S = 512, H = 768, G4 = 3072, H2 = 1536;
constexpr int FA_CH = 64, FA_ROWS = 8, FA_STG = 12;   // 8-row tiles + 4 halo
constexpr int FA_BLK = BC * FA_CH;      // 5120
constexpr int XF_BLK = 960, XB_BLK = 96;
constexpr int FRONT_BLK = FA_BLK + XF_BLK + XB_BLK;   // 6176
constexpr int NBACK = 96;               // cooperative back blocks
constexpr int HP = 772;                 // LDS row pad (dwords)
constexpr int CTR_N = 1600;             // 10 slots x 160 uints (8 grp lines + global)

typedef float f32x4 __attribute__((ext_vector_type(4)));

__device__ __forceinline__ float sigm(float x){ return 1.0f/(1.0f + __expf(-x)); }
__device__ __forceinline__ float tanh_fast(float x){ return 1.0f - 2.0f/(__expf(2.0f*x) + 1.0f); }
__device__ __forceinline__ float hsum(f32x4 a){ return (a.x+a.y)+(a.z+a.w); }
__device__ __forceinline__ float wred(float v){
  #pragma unroll
  for (int m = 32; m; m >>= 1) v += __shfl_xor(v, m, 64);
  return v;
}

// ---- coherent (cross-XCD via MALL) access: sc0 sc1 (R6-proven) ----
__device__ __forceinline__ void coh_load6(f32x4 (&d)[6],
    const f32x4* p0, const f32x4* p1, const f32x4* p2,
    const f32x4* p3, const f32x4* p4, const f32x4* p5){
  asm volatile(
    "global_load_dwordx4 %0, %6, off sc0 sc1\n\t"
    "global_load_dwordx4 %1, %7, off sc0 sc1\n\t"
    "global_load_dwordx4 %2, %8, off sc0 sc1\n\t"
    "global_load_dwordx4 %3, %9, off sc0 sc1\n\t"
    "global_load_dwordx4 %4, %10, off sc0 sc1\n\t"
    "global_load_dwordx4 %5, %11, off sc0 sc1\n\t"
    "s_waitcnt vmcnt(0)"
    : "=&v"(d[0]), "=&v"(d[1]), "=&v"(d[2]), "=&v"(d[3]), "=&v"(d[4]), "=&v"(d[5])
    : "v"(p0), "v"(p1), "v"(p2), "v"(p3), "v"(p4), "v"(p5)
    : "memory");
}
__device__ __forceinline__ void coh_store1(float* p, float v){
  asm volatile("global_store_dword %0, %1, off sc0 sc1" :: "v"(p), "v"(v) : "memory");
}

// ================= Kernel 1: fusedA || xgate (merged, 37 KB LDS) =============
__global__ __launch_bounds__(256) void k_front(
    const float* __restrict__ tok, const float* __restrict__ w_tok,
    const float* __restrict__ b_tok, float* __restrict__ win_out,
    float* __restrict__ wpart,
    const float* __restrict__ w_ih_f, const float* __restrict__ b_ih_f, const float* __restrict__ b_hh_f,
    const float* __restrict__ w_ih_b, const float* __restrict__ b_ih_b, const float* __restrict__ b_hh_b,
    float* __restrict__ xg, float* __restrict__ gbwd, unsigned* __restrict__ ctr){
  __shared__ float smemF[FA_STG * HP];   // 37056 B
  __shared__ float scr[FA_STG];
  __shared__ float wsh[FA_ROWS];
  int blk = blockIdx.x, tid = threadIdx.x;

  if (blk == 0) for (int i = tid; i < CTR_N; i += 256) ctr[i] = 0;

  if (blk < FA_BLK){
    // ---------- fusedA (R11-verbatim) ----------
    int bc = blk >> 6, ch = blk & 63;
    int s0 = ch * FA_ROWS;
    #pragma unroll
    for (int i = 0; i < 9; i++){                  // stage 12 rows (halo +-2)
      int f = i * 256 + tid;
      int row = f / 192, c4 = f % 192;
      int gs = s0 - 2 + row;
      if (gs >= 0 && gs < S)
        *(f32x4*)&smemF[row * HP + c4 * 4] =
          *(const f32x4*)&tok[((size_t)bc * S + gs) * H + c4 * 4];
    }
    __syncthreads();
    if (tid < 192){                               // scores: 12 rows x 16 lanes
      int r = tid >> 4, e = tid & 15;
      int gs = s0 - 2 + r;
      const f32x4* wq = (const f32x4*)w_tok;
      f32x4 a4 = {0.f, 0.f, 0.f, 0.f};
      #pragma unroll
      for (int i = 0; i < 12; i++){
        int k = e + 16 * i;
        a4 += *(const f32x4*)&smemF[r * HP + k * 4] * wq[k];
      }
      float acc = hsum(a4);
      acc += __shfl_xor(acc, 1, 64);
      acc += __shfl_xor(acc, 2, 64);
      acc += __shfl_xor(acc, 4, 64);
      acc += __shfl_xor(acc, 8, 64);
      if (e == 0) scr[r] = (gs >= 0 && gs < S) ? sigm(acc + b_tok[0]) : 0.f;
    }
    __syncthreads();
    if (tid < FA_ROWS){
      float w = (scr[tid] + scr[tid+1] + scr[tid+2] + scr[tid+3] + scr[tid+4]) * 0.2f;
      wsh[tid] = w;
      win_out[(size_t)bc * S + s0 + tid] = w;
    }
    __syncthreads();
    if (tid < 192){                               // weighted partial over 8 rows
      f32x4 acc = {0.f, 0.f, 0.f, 0.f};
      #pragma unroll
      for (int i = 0; i < FA_ROWS; i++){
        float w = wsh[i];
        f32x4 a = *(const f32x4*)&smemF[(i + 2) * HP + tid * 4];
        acc += a * w;
      }
      *(f32x4*)&wpart[((size_t)ch * BC + bc) * H + tid * 4] = acc;
    }
    return;
  }

  // ---------- xgate (R11-verbatim, uses first 8 rows of smemF) ----------
  int xb = blk - FA_BLK;
  bool fwd = (xb < XF_BLK);
  int rblk, base_bc = 0;
  const float *w, *bi, *bh; float* outp;
  if (fwd){ rblk = xb / 10; base_bc = (xb % 10) * 8; w = w_ih_f; bi = b_ih_f; bh = b_hh_f; outp = xg; }
  else    { rblk = xb - XF_BLK;                      w = w_ih_b; bi = b_ih_b; bh = b_hh_b; outp = gbwd; }
  #pragma unroll
  for (int i = 0; i < 6; i++){                   // stage 8 tok rows
    int f = i * 256 + tid;
    int bl = f / 192, c4 = f % 192;
    size_t bc = fwd ? (size_t)(base_bc + bl) : ((size_t)bl * NC + NC - 1);
    *(f32x4*)&smemF[bl * HP + c4 * 4] = *(const f32x4*)&tok[bc * (size_t)S * H + c4 * 4];
  }
  __syncthreads();
  {
    int bl = tid & 7, rl = tid >> 3;
    int r = rblk * 32 + rl;
    const f32x4* wr = (const f32x4*)(w + (size_t)r * H);
    f32x4 a4 = {0.f, 0.f, 0.f, 0.f};
    #pragma unroll 8
    for (int k = 0; k < 192; k++)
      a4 += *(const f32x4*)&smemF[bl * HP + k * 4] * wr[k];
    int ob = fwd ? (base_bc + bl) : bl;
    outp[(size_t)ob * G4 + r] = hsum(a4) + bi[r] + bh[r];
  }
}

// ================= Kernel 2: cooperative back, tree barrier ==================
struct BackArgs {
  const float *w_sum, *b_sum, *w_proj, *b_proj;
  const float *w_hh, *xg, *gbwd, *w_cls, *b_cls, *wpart;
  float *wmean, *s1, *summ_out, *hx, *cls_out;
  unsigned *ctr;
};

__global__ __launch_bounds__(256) void k_back(BackArgs A){
  __shared__ float smem[37696];                  // 150.8 KB total
  float* w_sh  = smem;                           // [32][772] w_hh rows (98.8 KB)
  float* h_sh  = smem + 24704;                   // [8][772]
  float* a_sh  = smem + 30880;                   // [8][772]
  float* c_sh  = smem + 37056;                   // [64]
  float* g_sh  = smem + 37120;                   // [8jl][4g][8b] = 256
  float* pg_sh = smem + 37376;                   // [64][5] = 320
  int tid = threadIdx.x, lane = tid & 63, wv = tid >> 6, blkx = blockIdx.x;

  // tree barrier: 8 group lines (12 arrivals each) + 1 global line
  auto gbar = [&](int slot){
    asm volatile("s_waitcnt vmcnt(0)" ::: "memory");
    __syncthreads();
    if (tid == 0){
      unsigned* base = A.ctr + slot * 160;
      int grp = blkx / 12;
      unsigned old = __hip_atomic_fetch_add(&base[grp * 16], 1u,
                        __ATOMIC_RELAXED, __HIP_MEMORY_SCOPE_AGENT);
      if (old == 11u)
        __hip_atomic_fetch_add(&base[128], 1u, __ATOMIC_RELAXED, __HIP_MEMORY_SCOPE_AGENT);
      while (__hip_atomic_load(&base[128], __ATOMIC_RELAXED, __HIP_MEMORY_SCOPE_AGENT) < 8u)
        __builtin_amdgcn_s_sleep(1);
    }
    __syncthreads();
  };

  auto stage6 = [&](float* dst, const float* src){
    const f32x4* s4 = (const f32x4*)src;
    f32x4 d[6];
    coh_load6(d, s4 + tid, s4 + 256 + tid, s4 + 512 + tid,
                 s4 + 768 + tid, s4 + 1024 + tid, s4 + 1280 + tid);
    #pragma unroll
    for (int i = 0; i < 6; i++){
      int f = i * 256 + tid, b = f / 192, j4 = f % 192;
      *(f32x4*)&dst[b * HP + j4 * 4] = d[i];
    }
  };

  // ---- preload w_hh rows (once): lr = jl*4 + g ----
  #pragma unroll
  for (int i = 0; i < 24; i++){
    int f = i * 256 + tid;
    int lr = f / 192, k = f % 192;
    int g = lr & 3, jl = lr >> 2;
    int r = g * H + blkx * 8 + jl;
    *(f32x4*)&w_sh[lr * HP + k * 4] = *(const f32x4*)&A.w_hh[(size_t)r * H + k * 4];
  }

  // hoisted step mapping (thread = (lr = tid>>3, b = tid&7))
  int sb = tid & 7, slr = tid >> 3;
  int sjl = slr >> 2, sg = slr & 3;
  int sr = sg * H + blkx * 8 + sjl;
  size_t xgrow = (size_t)sb * NC;

  // step t with prefetched xg value
  auto do_step = [&](int t, float xgv){
    const f32x4* wr = (const f32x4*)&w_sh[slr * HP];
    const f32x4* hb = (const f32x4*)&h_sh[sb * HP];
    f32x4 a4 = {0.f, 0.f, 0.f, 0.f};
    #pragma unroll 8
    for (int k = 0; k < 192; k++)
      a4 += wr[k] * hb[k];
    g_sh[sjl * 32 + sg * 8 + sb] = hsum(a4) + xgv;
    __syncthreads();
    if (tid < 64){
      int jj = tid >> 3, b2 = tid & 7;
      float gi = g_sh[jj*32 + b2],      gf = g_sh[jj*32 + 8 + b2];
      float gg = g_sh[jj*32 + 16 + b2], go = g_sh[jj*32 + 24 + b2];
      float c = sigm(gf) * c_sh[tid] + sigm(gi) * tanh_fast(gg);
      c_sh[tid] = c;
      coh_store1(&A.hx[(t & 1) * (Bsz*H) + b2 * H + blkx * 8 + jj],
                 sigm(go) * tanh_fast(c));
    }
  };

  // ---- P0: wmean (parallel partials over 64 chunks) + LSTM init ----
  {
    int out = tid >> 2, ps = tid & 3;            // 64 outputs x 4 p-slices
    int idx = blkx * 64 + out;
    int b = idx / H, hh = idx % H;
    float acc = 0.f;
    for (int p = ps * 16; p < ps * 16 + 16; p++)
      #pragma unroll
      for (int c = 0; c < NC; c++)
        acc += A.wpart[((size_t)p * BC + b * NC + c) * H + hh];
    pg_sh[out * 5 + ps] = acc;
  }
  __syncthreads();
  if (tid < 64){
    float acc = pg_sh[tid*5] + pg_sh[tid*5+1] + pg_sh[tid*5+2] + pg_sh[tid*5+3];
    coh_store1(&A.wmean[blkx * 64 + tid], acc * 0.1f);
    int jl = tid >> 3, b2 = tid & 7, j = blkx * 8 + jl;
    const float* gp = A.xg + (size_t)(b2 * NC) * G4;
    float c = sigm(gp[j]) * tanh_fast(gp[2*H + j]);
    c_sh[tid] = c;
    coh_store1(&A.hx[b2 * H + j], sigm(gp[3*H + j]) * tanh_fast(c));
  }
  float xgv = A.xg[(xgrow + 1) * G4 + sr];       // prefetch step1
  gbar(0);

  // ---- P1: s1 = wmean @ w_sum.T  ||  step1 ----
  stage6(a_sh, A.wmean);
  stage6(h_sh, A.hx);            // h1 (buf 0)
  __syncthreads();
  {
    int out = tid >> 2, q = tid & 3;
    int ol = out >> 3, b = out & 7;
    int o = blkx * 8 + ol;
    const f32x4* wq = (const f32x4*)(A.w_sum + (size_t)o * H) + q * 48;
    f32x4 a4 = {0.f, 0.f, 0.f, 0.f};
    #pragma unroll 8
    for (int k = 0; k < 48; k++)
      a4 += *(const f32x4*)&a_sh[b * HP + (q * 48 + k) * 4] * wq[k];
    float acc = hsum(a4);
    acc += __shfl_xor(acc, 1, 64);
    acc += __shfl_xor(acc, 2, 64);
    if (q == 0) coh_store1(&A.s1[(size_t)b * H + o], acc + A.b_sum[o]);
  }
  do_step(1, xgv);
  xgv = A.xg[(xgrow + 2) * G4 + sr];             // prefetch step2
  gbar(1);

  // ---- P2: summ = s1 @ w_proj.T  ||  step2 ----
  stage6(a_sh, A.s1);
  stage6(h_sh, A.hx + Bsz*H);    // h2 (buf 1)
  __syncthreads();
  {
    int out = tid >> 1, hf = tid & 1;
    int ol = out >> 3, b = out & 7;
    int o = blkx * 16 + ol;
    const f32x4* wq = (const f32x4*)(A.w_proj + (size_t)o * H) + hf * 96;
    f32x4 a4 = {0.f, 0.f, 0.f, 0.f};
    #pragma unroll 8
    for (int k = 0; k < 96; k++)
      a4 += *(const f32x4*)&a_sh[b * HP + (hf * 96 + k) * 4] * wq[k];
    float acc = hsum(a4);
    acc += __shfl_xor(acc, 1, 64);
    if (hf == 0) coh_store1(&A.summ_out[(size_t)b * H2 + o], acc + A.b_proj[o]);
  }
  do_step(2, xgv);
  xgv = A.xg[(xgrow + 3) * G4 + sr];             // prefetch step3
  gbar(2);

  // ---- steps 3..9 ----
  for (int t = 3; t <= 9; t++){
    stage6(h_sh, A.hx + ((t - 1) & 1) * (Bsz*H));
    __syncthreads();
    do_step(t, xgv);
    if (t < 9) xgv = A.xg[(xgrow + t + 1) * G4 + sr];
    gbar(t);
  }

  // ---- fincls on block 0: comb = [h10|hb] + summ ; cls ----
  if (blkx == 0){
    float* comb = smem;                          // 12288 floats (reuses w_sh)
    {
      f32x4 d[6];
      const f32x4* h4 = (const f32x4*)(A.hx + Bsz*H);   // h10 (buf 1)
      coh_load6(d, h4 + tid, h4 + 256 + tid, h4 + 512 + tid,
                   h4 + 768 + tid, h4 + 1024 + tid, h4 + 1280 + tid);
      #pragma unroll
      for (int i = 0; i < 6; i++){
        int f = i * 256 + tid, b = f / 192, e = (f % 192) * 4;
        *(f32x4*)&comb[b * H2 + e] = d[i];
      }
      #pragma unroll
      for (int u = 0; u < 6; u++){               // hb from gbwd (plain loads)
        int f = u * 256 + tid;
        int b = f / 192, e = (f % 192) * 4;
        f32x4 gi = *(const f32x4*)&A.gbwd[(size_t)b * G4 + e];
        f32x4 gg = *(const f32x4*)&A.gbwd[(size_t)b * G4 + 2*H + e];
        f32x4 go = *(const f32x4*)&A.gbwd[(size_t)b * G4 + 3*H + e];
        f32x4 hb;
        hb.x = sigm(go.x) * tanh_fast(sigm(gi.x) * tanh_fast(gg.x));
        hb.y = sigm(go.y) * tanh_fast(sigm(gi.y) * tanh_fast(gg.y));
        hb.z = sigm(go.z) * tanh_fast(sigm(gi.z) * tanh_fast(gg.z));
        hb.w = sigm(go.w) * tanh_fast(sigm(gi.w) * tanh_fast(gg.w));
        *(f32x4*)&comb[b * H2 + H + e] = hb;
      }
    }
    __syncthreads();
    {
      f32x4 d[6];
      const f32x4* s4 = (const f32x4*)A.summ_out;
      coh_load6(d, s4 + tid, s4 + 256 + tid, s4 + 512 + tid,
                   s4 + 768 + tid, s4 + 1024 + tid, s4 + 1280 + tid);
      #pragma unroll
      for (int i = 0; i < 6; i++) *(f32x4*)&comb[(i * 256 + tid) * 4] += d[i];
      coh_load6(d, s4 + 1536 + tid, s4 + 1792 + tid, s4 + 2048 + tid,
                   s4 + 2304 + tid, s4 + 2560 + tid, s4 + 2816 + tid);
      #pragma unroll
      for (int i = 0; i < 6; i++) *(f32x4*)&comb[(1536 + i * 256 + tid) * 4] += d[i];
    }
    __syncthreads();
    for (int b = wv; b < Bsz; b += 4){
      const f32x4* c4 = (const f32x4*)&comb[b * H2];
      const f32x4* wc = (const f32x4*)A.w_cls;
      f32x4 a4 = {0.f, 0.f, 0.f, 0.f};
      #pragma unroll
      for (int k = 0; k < 6; k++)
        a4 += c4[lane + 64*k] * wc[lane + 64*k];
      float acc = wred(hsum(a4));
      if (lane == 0) A.cls_out[b] = sigm(acc + A.b_cls[0]);
    }
  }
}

} // namespace

extern "C" void kernel_launch(void* const* d_in, const int* in_sizes, int n_in,
                              void* d_out, int out_size, void* d_ws, size_t ws_size,
                              hipStream_t stream) {
  const float* tok    = (const float*)d_in[0];
  const float* w_tok  = (const float*)d_in[1];
  const float* b_tok  = (const float*)d_in[2];
  const float* w_sum  = (const float*)d_in[3];
  const float* b_sum  = (const float*)d_in[4];
  const float* w_proj = (const float*)d_in[5];
  const float* b_proj = (const float*)d_in[6];
  const float* w_ih_f = (const float*)d_in[7];
  const float* w_hh_f = (const float*)d_in[8];
  const float* b_ih_f = (const float*)d_in[9];
  const float* b_hh_f = (const float*)d_in[10];
  const float* w_ih_b = (const float*)d_in[11];
  const float* b_ih_b = (const float*)d_in[13];
  const float* b_hh_b = (const float*)d_in[14];
  const float* w_cls  = (const float*)d_in[15];
  const float* b_cls  = (const float*)d_in[16];

  float* out      = (float*)d_out;
  float* cls_out  = out;
  float* win_out  = out + 8;
  float* summ_out = out + 8 + BC * S;

  float* ws     = (float*)d_ws;
  float* wpart  = ws;                              // 64*80*768
  float* wmean  = wpart + (size_t)FA_CH * BC * H;  // 6144
  float* s1     = wmean + Bsz * H;                 // 6144
  float* xg     = s1 + Bsz * H;                    // 245760
  float* gbwd   = xg + (size_t)BC * G4;            // 24576
  float* hx     = gbwd + (size_t)Bsz * G4;         // 12288 (2 bufs)
  unsigned* ctr = (unsigned*)(hx + 2 * Bsz * H);   // 1600 uints

  k_front<<<FRONT_BLK, 256, 0, stream>>>(tok, w_tok, b_tok, win_out, wpart,
                                         w_ih_f, b_ih_f, b_hh_f,
                                         w_ih_b, b_ih_b, b_hh_b, xg, gbwd, ctr);

  BackArgs ba;
  ba.w_sum = w_sum; ba.b_sum = b_sum; ba.w_proj = w_proj; ba.b_proj = b_proj;
  ba.w_hh = w_hh_f; ba.xg = xg; ba.gbwd = gbwd; ba.w_cls = w_cls; ba.b_cls = b_cls;
  ba.wpart = wpart; ba.wmean = wmean; ba.s1 = s1; ba.summ_out = summ_out;
  ba.hx = hx; ba.cls_out = cls_out; ba.ctr = ctr;

  void* params[] = { &ba };
  hipLaunchCooperativeKernel(reinterpret_cast<void*>(k_back),
                             dim3(NBACK), dim3(256), params, 0, stream);
}

// Round 14
// 171.516 us; speedup vs baseline: 1.5087x; 1.0266x over previous
//
#include <hip/hip_runtime.h>

namespace {

constexpr int Bsz = 8, NC = 10, BC = 80, S = 512, H = 768, G4 = 3072, H2 = 1536;
constexpr int FA_CH = 64, FA_ROWS = 8, FA_STG = 12;   // 8-row tiles + 4 halo
constexpr int FA_BLK = BC * FA_CH;      // 5120
constexpr int XF_BLK = 960, XB_BLK = 96;
constexpr int FRONT_BLK = FA_BLK + XF_BLK + XB_BLK;   // 6176
constexpr int NBACK = 192;              // cooperative back blocks (16 gate-rows each)
constexpr int HP = 772;                 // LDS row pad (dwords)
constexpr int CTR_STRIDE = 320;         // per-slot: 16 group lines + global line
constexpr int CTR_N = 10 * CTR_STRIDE;  // 3200

typedef float f32x4 __attribute__((ext_vector_type(4)));

__device__ __forceinline__ float sigm(float x){ return 1.0f/(1.0f + __expf(-x)); }
__device__ __forceinline__ float tanh_fast(float x){ return 1.0f - 2.0f/(__expf(2.0f*x) + 1.0f); }
__device__ __forceinline__ float hsum(f32x4 a){ return (a.x+a.y)+(a.z+a.w); }
__device__ __forceinline__ float wred(float v){
  #pragma unroll
  for (int m = 32; m; m >>= 1) v += __shfl_xor(v, m, 64);
  return v;
}

// ---- coherent (cross-XCD via MALL) access: sc0 sc1 (R6-proven) ----
__device__ __forceinline__ void coh_load6(f32x4 (&d)[6],
    const f32x4* p0, const f32x4* p1, const f32x4* p2,
    const f32x4* p3, const f32x4* p4, const f32x4* p5){
  asm volatile(
    "global_load_dwordx4 %0, %6, off sc0 sc1\n\t"
    "global_load_dwordx4 %1, %7, off sc0 sc1\n\t"
    "global_load_dwordx4 %2, %8, off sc0 sc1\n\t"
    "global_load_dwordx4 %3, %9, off sc0 sc1\n\t"
    "global_load_dwordx4 %4, %10, off sc0 sc1\n\t"
    "global_load_dwordx4 %5, %11, off sc0 sc1\n\t"
    "s_waitcnt vmcnt(0)"
    : "=&v"(d[0]), "=&v"(d[1]), "=&v"(d[2]), "=&v"(d[3]), "=&v"(d[4]), "=&v"(d[5])
    : "v"(p0), "v"(p1), "v"(p2), "v"(p3), "v"(p4), "v"(p5)
    : "memory");
}
__device__ __forceinline__ void coh_store1(float* p, float v){
  asm volatile("global_store_dword %0, %1, off sc0 sc1" :: "v"(p), "v"(v) : "memory");
}

// ================= Kernel 1: fusedA || xgate (merged) — R13-verbatim ========
__global__ __launch_bounds__(256) void k_front(
    const float* __restrict__ tok, const float* __restrict__ w_tok,
    const float* __restrict__ b_tok, float* __restrict__ win_out,
    float* __restrict__ wpart,
    const float* __restrict__ w_ih_f, const float* __restrict__ b_ih_f, const float* __restrict__ b_hh_f,
    const float* __restrict__ w_ih_b, const float* __restrict__ b_ih_b, const float* __restrict__ b_hh_b,
    float* __restrict__ xg, float* __restrict__ gbwd, unsigned* __restrict__ ctr){
  __shared__ float smemF[FA_STG * HP];   // 37056 B
  __shared__ float scr[FA_STG];
  __shared__ float wsh[FA_ROWS];
  int blk = blockIdx.x, tid = threadIdx.x;

  if (blk == 0) for (int i = tid; i < CTR_N; i += 256) ctr[i] = 0;

  if (blk < FA_BLK){
    int bc = blk >> 6, ch = blk & 63;
    int s0 = ch * FA_ROWS;
    #pragma unroll
    for (int i = 0; i < 9; i++){                  // stage 12 rows (halo +-2)
      int f = i * 256 + tid;
      int row = f / 192, c4 = f % 192;
      int gs = s0 - 2 + row;
      if (gs >= 0 && gs < S)
        *(f32x4*)&smemF[row * HP + c4 * 4] =
          *(const f32x4*)&tok[((size_t)bc * S + gs) * H + c4 * 4];
    }
    __syncthreads();
    if (tid < 192){                               // scores: 12 rows x 16 lanes
      int r = tid >> 4, e = tid & 15;
      int gs = s0 - 2 + r;
      const f32x4* wq = (const f32x4*)w_tok;
      f32x4 a4 = {0.f, 0.f, 0.f, 0.f};
      #pragma unroll
      for (int i = 0; i < 12; i++){
        int k = e + 16 * i;
        a4 += *(const f32x4*)&smemF[r * HP + k * 4] * wq[k];
      }
      float acc = hsum(a4);
      acc += __shfl_xor(acc, 1, 64);
      acc += __shfl_xor(acc, 2, 64);
      acc += __shfl_xor(acc, 4, 64);
      acc += __shfl_xor(acc, 8, 64);
      if (e == 0) scr[r] = (gs >= 0 && gs < S) ? sigm(acc + b_tok[0]) : 0.f;
    }
    __syncthreads();
    if (tid < FA_ROWS){
      float w = (scr[tid] + scr[tid+1] + scr[tid+2] + scr[tid+3] + scr[tid+4]) * 0.2f;
      wsh[tid] = w;
      win_out[(size_t)bc * S + s0 + tid] = w;
    }
    __syncthreads();
    if (tid < 192){                               // weighted partial over 8 rows
      f32x4 acc = {0.f, 0.f, 0.f, 0.f};
      #pragma unroll
      for (int i = 0; i < FA_ROWS; i++){
        float w = wsh[i];
        f32x4 a = *(const f32x4*)&smemF[(i + 2) * HP + tid * 4];
        acc += a * w;
      }
      *(f32x4*)&wpart[((size_t)ch * BC + bc) * H + tid * 4] = acc;
    }
    return;
  }

  int xb = blk - FA_BLK;
  bool fwd = (xb < XF_BLK);
  int rblk, base_bc = 0;
  const float *w, *bi, *bh; float* outp;
  if (fwd){ rblk = xb / 10; base_bc = (xb % 10) * 8; w = w_ih_f; bi = b_ih_f; bh = b_hh_f; outp = xg; }
  else    { rblk = xb - XF_BLK;                      w = w_ih_b; bi = b_ih_b; bh = b_hh_b; outp = gbwd; }
  #pragma unroll
  for (int i = 0; i < 6; i++){                   // stage 8 tok rows
    int f = i * 256 + tid;
    int bl = f / 192, c4 = f % 192;
    size_t bc = fwd ? (size_t)(base_bc + bl) : ((size_t)bl * NC + NC - 1);
    *(f32x4*)&smemF[bl * HP + c4 * 4] = *(const f32x4*)&tok[bc * (size_t)S * H + c4 * 4];
  }
  __syncthreads();
  {
    int bl = tid & 7, rl = tid >> 3;
    int r = rblk * 32 + rl;
    const f32x4* wr = (const f32x4*)(w + (size_t)r * H);
    f32x4 a4 = {0.f, 0.f, 0.f, 0.f};
    #pragma unroll 8
    for (int k = 0; k < 192; k++)
      a4 += *(const f32x4*)&smemF[bl * HP + k * 4] * wr[k];
    int ob = fwd ? (base_bc + bl) : bl;
    outp[(size_t)ob * G4 + r] = hsum(a4) + bi[r] + bh[r];
  }
}

// ================= Kernel 2: cooperative back, 192 blocks, kh-split ==========
struct BackArgs {
  const float *w_sum, *b_sum, *w_proj, *b_proj;
  const float *w_hh, *xg, *gbwd, *w_cls, *b_cls, *wpart;
  float *wmean, *s1, *summ_out, *hx, *cls_out;
  unsigned *ctr;
};

__global__ __launch_bounds__(256) void k_back(BackArgs A){
  __shared__ float smem[25152];                  // 100.6 KB total
  float* w_sh  = smem;                           // [16][772] w_hh rows (49.4 KB)
  float* h_sh  = smem + 12352;                   // [8][772]
  float* a_sh  = smem + 18528;                   // [8][772]
  float* c_sh  = smem + 24704;                   // [32]
  float* g_sh  = smem + 24736;                   // [4jl][4g][8b] = 128
  float* pg_sh = smem + 24864;                   // [32][9] = 288
  int tid = threadIdx.x, lane = tid & 63, wv = tid >> 6, blkx = blockIdx.x;

  // tree barrier: 16 group lines (12 arrivals each) + 1 global line
  auto gbar = [&](int slot){
    asm volatile("s_waitcnt vmcnt(0)" ::: "memory");
    __syncthreads();
    if (tid == 0){
      unsigned* base = A.ctr + slot * CTR_STRIDE;
      int grp = blkx / 12;
      unsigned old = __hip_atomic_fetch_add(&base[grp * 16], 1u,
                        __ATOMIC_RELAXED, __HIP_MEMORY_SCOPE_AGENT);
      if (old == 11u)
        __hip_atomic_fetch_add(&base[256], 1u, __ATOMIC_RELAXED, __HIP_MEMORY_SCOPE_AGENT);
      while (__hip_atomic_load(&base[256], __ATOMIC_RELAXED, __HIP_MEMORY_SCOPE_AGENT) < 16u)
        __builtin_amdgcn_s_sleep(1);
    }
    __syncthreads();
  };

  auto stage6 = [&](float* dst, const float* src){
    const f32x4* s4 = (const f32x4*)src;
    f32x4 d[6];
    coh_load6(d, s4 + tid, s4 + 256 + tid, s4 + 512 + tid,
                 s4 + 768 + tid, s4 + 1024 + tid, s4 + 1280 + tid);
    #pragma unroll
    for (int i = 0; i < 6; i++){
      int f = i * 256 + tid, b = f / 192, j4 = f % 192;
      *(f32x4*)&dst[b * HP + j4 * 4] = d[i];
    }
  };

  // ---- preload 16 w_hh rows (once): lr = jl*4 + g ----
  #pragma unroll
  for (int i = 0; i < 12; i++){
    int f = i * 256 + tid;          // 0..3071 f32x4 units
    int lr = f / 192, k = f % 192;
    int g = lr & 3, jl = lr >> 2;
    int r = g * H + blkx * 4 + jl;
    *(f32x4*)&w_sh[lr * HP + k * 4] = *(const f32x4*)&A.w_hh[(size_t)r * H + k * 4];
  }

  // step mapping: tid = lr*16 + b*2 + kh
  int skh = tid & 1, sb = (tid >> 1) & 7, slr = tid >> 4;
  int sjl = slr >> 2, sg = slr & 3;
  int sr = sg * H + blkx * 4 + sjl;
  size_t xgrow = (size_t)sb * NC;

  // step t with prefetched xg value; kh-partners combine via shfl_xor(1)
  auto do_step = [&](int t, float xgv){
    const f32x4* wr = (const f32x4*)&w_sh[slr * HP] + skh * 96;
    const f32x4* hb = (const f32x4*)&h_sh[sb * HP] + skh * 96;
    f32x4 a4 = {0.f, 0.f, 0.f, 0.f};
    #pragma unroll 8
    for (int k = 0; k < 96; k++)
      a4 += wr[k] * hb[k];
    float p = hsum(a4);
    p += __shfl_xor(p, 1, 64);
    if (skh == 0) g_sh[sjl * 32 + sg * 8 + sb] = p + xgv;
    __syncthreads();
    if (tid < 32){
      int jj = tid >> 3, b2 = tid & 7;
      float gi = g_sh[jj*32 + b2],      gf = g_sh[jj*32 + 8 + b2];
      float gg = g_sh[jj*32 + 16 + b2], go = g_sh[jj*32 + 24 + b2];
      float c = sigm(gf) * c_sh[tid] + sigm(gi) * tanh_fast(gg);
      c_sh[tid] = c;
      coh_store1(&A.hx[(t & 1) * (Bsz*H) + b2 * H + blkx * 4 + jj],
                 sigm(go) * tanh_fast(c));
    }
  };

  // ---- P0: wmean (32 outputs x 8 p-slices) + LSTM init ----
  {
    int out = tid >> 3, ps = tid & 7;
    int idx = blkx * 32 + out;
    int b = idx / H, hh = idx % H;
    float acc = 0.f;
    for (int p = ps * 8; p < ps * 8 + 8; p++)
      #pragma unroll
      for (int c = 0; c < NC; c++)
        acc += A.wpart[((size_t)p * BC + b * NC + c) * H + hh];
    pg_sh[out * 9 + ps] = acc;
  }
  __syncthreads();
  if (tid < 32){
    float acc = 0.f;
    #pragma unroll
    for (int ps = 0; ps < 8; ps++) acc += pg_sh[tid * 9 + ps];
    coh_store1(&A.wmean[blkx * 32 + tid], acc * 0.1f);
    int jl = tid >> 3, b2 = tid & 7, j = blkx * 4 + jl;
    const float* gp = A.xg + (size_t)(b2 * NC) * G4;
    float c = sigm(gp[j]) * tanh_fast(gp[2*H + j]);
    c_sh[tid] = c;
    coh_store1(&A.hx[b2 * H + j], sigm(gp[3*H + j]) * tanh_fast(c));
  }
  float xgv = A.xg[(xgrow + 1) * G4 + sr];       // prefetch step1
  gbar(0);

  // ---- P1: s1 = wmean @ w_sum.T (4 o x 8 b x 8 q)  ||  step1 ----
  stage6(a_sh, A.wmean);
  stage6(h_sh, A.hx);            // h1 (buf 0)
  __syncthreads();
  {
    int ol = tid >> 6, b = (tid >> 3) & 7, q = tid & 7;
    int o = blkx * 4 + ol;
    const f32x4* wq = (const f32x4*)(A.w_sum + (size_t)o * H) + q * 24;
    f32x4 a4 = {0.f, 0.f, 0.f, 0.f};
    #pragma unroll 8
    for (int k = 0; k < 24; k++)
      a4 += *(const f32x4*)&a_sh[b * HP + (q * 24 + k) * 4] * wq[k];
    float acc = hsum(a4);
    acc += __shfl_xor(acc, 1, 64);
    acc += __shfl_xor(acc, 2, 64);
    acc += __shfl_xor(acc, 4, 64);
    if (q == 0) coh_store1(&A.s1[(size_t)b * H + o], acc + A.b_sum[o]);
  }
  do_step(1, xgv);
  xgv = A.xg[(xgrow + 2) * G4 + sr];             // prefetch step2
  gbar(1);

  // ---- P2: summ = s1 @ w_proj.T (8 o x 8 b x 4 q)  ||  step2 ----
  stage6(a_sh, A.s1);
  stage6(h_sh, A.hx + Bsz*H);    // h2 (buf 1)
  __syncthreads();
  {
    int ol = tid >> 5, b = (tid >> 2) & 7, q = tid & 3;
    int o = blkx * 8 + ol;
    const f32x4* wq = (const f32x4*)(A.w_proj + (size_t)o * H) + q * 48;
    f32x4 a4 = {0.f, 0.f, 0.f, 0.f};
    #pragma unroll 8
    for (int k = 0; k < 48; k++)
      a4 += *(const f32x4*)&a_sh[b * HP + (q * 48 + k) * 4] * wq[k];
    float acc = hsum(a4);
    acc += __shfl_xor(acc, 1, 64);
    acc += __shfl_xor(acc, 2, 64);
    if (q == 0) coh_store1(&A.summ_out[(size_t)b * H2 + o], acc + A.b_proj[o]);
  }
  do_step(2, xgv);
  xgv = A.xg[(xgrow + 3) * G4 + sr];             // prefetch step3
  gbar(2);

  // ---- steps 3..9 ----
  for (int t = 3; t <= 9; t++){
    stage6(h_sh, A.hx + ((t - 1) & 1) * (Bsz*H));
    __syncthreads();
    do_step(t, xgv);
    if (t < 9) xgv = A.xg[(xgrow + t + 1) * G4 + sr];
    gbar(t);
  }

  // ---- fincls on block 0: comb = [h10|hb] + summ ; cls ----
  if (blkx == 0){
    float* comb = smem;                          // 12288 floats (reuses w_sh)
    {
      f32x4 d[6];
      const f32x4* h4 = (const f32x4*)(A.hx + Bsz*H);   // h10 (buf 1)
      coh_load6(d, h4 + tid, h4 + 256 + tid, h4 + 512 + tid,
                   h4 + 768 + tid, h4 + 1024 + tid, h4 + 1280 + tid);
      #pragma unroll
      for (int i = 0; i < 6; i++){
        int f = i * 256 + tid, b = f / 192, e = (f % 192) * 4;
        *(f32x4*)&comb[b * H2 + e] = d[i];
      }
      #pragma unroll
      for (int u = 0; u < 6; u++){               // hb from gbwd (plain loads)
        int f = u * 256 + tid;
        int b = f / 192, e = (f % 192) * 4;
        f32x4 gi = *(const f32x4*)&A.gbwd[(size_t)b * G4 + e];
        f32x4 gg = *(const f32x4*)&A.gbwd[(size_t)b * G4 + 2*H + e];
        f32x4 go = *(const f32x4*)&A.gbwd[(size_t)b * G4 + 3*H + e];
        f32x4 hb;
        hb.x = sigm(go.x) * tanh_fast(sigm(gi.x) * tanh_fast(gg.x));
        hb.y = sigm(go.y) * tanh_fast(sigm(gi.y) * tanh_fast(gg.y));
        hb.z = sigm(go.z) * tanh_fast(sigm(gi.z) * tanh_fast(gg.z));
        hb.w = sigm(go.w) * tanh_fast(sigm(gi.w) * tanh_fast(gg.w));
        *(f32x4*)&comb[b * H2 + H + e] = hb;
      }
    }
    __syncthreads();
    {
      f32x4 d[6];
      const f32x4* s4 = (const f32x4*)A.summ_out;
      coh_load6(d, s4 + tid, s4 + 256 + tid, s4 + 512 + tid,
                   s4 + 768 + tid, s4 + 1024 + tid, s4 + 1280 + tid);
      #pragma unroll
      for (int i = 0; i < 6; i++) *(f32x4*)&comb[(i * 256 + tid) * 4] += d[i];
      coh_load6(d, s4 + 1536 + tid, s4 + 1792 + tid, s4 + 2048 + tid,
                   s4 + 2304 + tid, s4 + 2560 + tid, s4 + 2816 + tid);
      #pragma unroll
      for (int i = 0; i < 6; i++) *(f32x4*)&comb[(1536 + i * 256 + tid) * 4] += d[i];
    }
    __syncthreads();
    for (int b = wv; b < Bsz; b += 4){
      const f32x4* c4 = (const f32x4*)&comb[b * H2];
      const f32x4* wc = (const f32x4*)A.w_cls;
      f32x4 a4 = {0.f, 0.f, 0.f, 0.f};
      #pragma unroll
      for (int k = 0; k < 6; k++)
        a4 += c4[lane + 64*k] * wc[lane + 64*k];
      float acc = wred(hsum(a4));
      if (lane == 0) A.cls_out[b] = sigm(acc + A.b_cls[0]);
    }
  }
}

} // namespace

extern "C" void kernel_launch(void* const* d_in, const int* in_sizes, int n_in,
                              void* d_out, int out_size, void* d_ws, size_t ws_size,
                              hipStream_t stream) {
  const float* tok    = (const float*)d_in[0];
  const float* w_tok  = (const float*)d_in[1];
  const float* b_tok  = (const float*)d_in[2];
  const float* w_sum  = (const float*)d_in[3];
  const float* b_sum  = (const float*)d_in[4];
  const float* w_proj = (const float*)d_in[5];
  const float* b_proj = (const float*)d_in[6];
  const float* w_ih_f = (const float*)d_in[7];
  const float* w_hh_f = (const float*)d_in[8];
  const float* b_ih_f = (const float*)d_in[9];
  const float* b_hh_f = (const float*)d_in[10];
  const float* w_ih_b = (const float*)d_in[11];
  const float* b_ih_b = (const float*)d_in[13];
  const float* b_hh_b = (const float*)d_in[14];
  const float* w_cls  = (const float*)d_in[15];
  const float* b_cls  = (const float*)d_in[16];

  float* out      = (float*)d_out;
  float* cls_out  = out;
  float* win_out  = out + 8;
  float* summ_out = out + 8 + BC * S;

  float* ws     = (float*)d_ws;
  float* wpart  = ws;                              // 64*80*768
  float* wmean  = wpart + (size_t)FA_CH * BC * H;  // 6144
  float* s1     = wmean + Bsz * H;                 // 6144
  float* xg     = s1 + Bsz * H;                    // 245760
  float* gbwd   = xg + (size_t)BC * G4;            // 24576
  float* hx     = gbwd + (size_t)Bsz * G4;         // 12288 (2 bufs)
  unsigned* ctr = (unsigned*)(hx + 2 * Bsz * H);   // 3200 uints

  k_front<<<FRONT_BLK, 256, 0, stream>>>(tok, w_tok, b_tok, win_out, wpart,
                                         w_ih_f, b_ih_f, b_hh_f,
                                         w_ih_b, b_ih_b, b_hh_b, xg, gbwd, ctr);

  BackArgs ba;
  ba.w_sum = w_sum; ba.b_sum = b_sum; ba.w_proj = w_proj; ba.b_proj = b_proj;
  ba.w_hh = w_hh_f; ba.xg = xg; ba.gbwd = gbwd; ba.w_cls = w_cls; ba.b_cls = b_cls;
  ba.wpart = wpart; ba.wmean = wmean; ba.s1 = s1; ba.summ_out = summ_out;
  ba.hx = hx; ba.cls_out = cls_out; ba.ctr = ctr;

  void* params[] = { &ba };
  hipLaunchCooperativeKernel(reinterpret_cast<void*>(k_back),
                             dim3(NBACK), dim3(256), params, 0, stream);
}